// Round 1
// baseline (2308.451 us; speedup 1.0000x reference)
//
#include <hip/hip_runtime.h>
#include <math.h>

// Problem constants (fixed by setup_inputs: B=32, H=480, W=640)
#define BB 32
#define HH 480
#define WW 640
#define HWN (HH * WW)
#define OH 34            // H // RESHAPE
#define OW 45            // W // RESHAPE
#define OHW (OH * OW)    // 1530
#define KTOP 153         // max(int(0.1*oh*ow), 10)
#define KS 25            // kernel size (odd)
#define PHW 12           // half kernel
#define PATCH (KS * KS)  // 625
#define RESHAPE_I 14
#define EPSV 1e-5f

// ---------- monotone float <-> uint key ----------
__device__ __forceinline__ unsigned int fkey(float f) {
  unsigned int u = __float_as_uint(f);
  return (u & 0x80000000u) ? ~u : (u | 0x80000000u);
}
__device__ __forceinline__ float fkey_inv(unsigned int k) {
  unsigned int u = (k & 0x80000000u) ? (k & 0x7FFFFFFFu) : ~k;
  return __uint_as_float(u);
}

// ---------- 256-thread block reduce ----------
__device__ __forceinline__ float breduce256(float v, float* red) {
  const int t = threadIdx.x;
  __syncthreads();
  red[t] = v;
  __syncthreads();
  for (int s2 = 128; s2 > 0; s2 >>= 1) {
    if (t < s2) red[t] += red[t + s2];
    __syncthreads();
  }
  float r = red[0];
  __syncthreads();
  return r;
}

// ---------- edge value at (b, y, x): sobel + erode(validity) + border mask ----------
__device__ float edge_at(const float* __restrict__ image, const unsigned char* __restrict__ vmask,
                         int b, int y, int x) {
  // border mask: 1 only for 3 <= y < H-3, 3 <= x < W-3
  if (y < 3 || y >= HH - 3 || x < 3 || x >= WW - 3) return 0.f;
  // erode3 of validity: all 9 neighbors true (y,x interior guaranteed by above)
  const unsigned char* vm = vmask + (size_t)b * HWN;
  #pragma unroll
  for (int dy = -1; dy <= 1; ++dy) {
    #pragma unroll
    for (int dx = -1; dx <= 1; ++dx) {
      if (!vm[(size_t)(y + dy) * WW + (x + dx)]) return 0.f;
    }
  }
  const float* img = image + (size_t)b * 3 * HWN;
  float sx2 = 0.f, sy2 = 0.f;
  #pragma unroll
  for (int c = 0; c < 3; ++c) {
    const float* p = img + (size_t)c * HWN + (size_t)y * WW + x;
    float a00 = p[-WW - 1], a01 = p[-WW], a02 = p[-WW + 1];
    float a10 = p[-1],                    a12 = p[1];
    float a20 = p[WW - 1],  a21 = p[WW],  a22 = p[WW + 1];
    // cross-correlation with SOBEL_X / SOBEL_Y, tap order (ky,kx), /8
    float gx = (-a00 + a02 + -2.f * a10 + 2.f * a12 + -a20 + a22) / 8.f;
    float gy = (-a00 + -2.f * a01 + -a02 + a20 + 2.f * a21 + a22) / 8.f;
    sx2 += gx * gx;
    sy2 += gy * gy;
  }
  float gxm = sqrtf(sx2 / 3.f);
  float gym = sqrtf(sy2 / 3.f);
  return sqrtf(gxm * gxm + gym * gym);
}

// ---------- K1: fused edge + bilinear resize to (OH, OW) ----------
__global__ __launch_bounds__(256) void edge_resize_kernel(const float* __restrict__ image,
                                                          const unsigned char* __restrict__ vmask,
                                                          float* __restrict__ re) {
  int id = blockIdx.x * 256 + threadIdx.x;
  if (id >= BB * OHW) return;
  int b = id / OHW;
  int rem = id % OHW;
  int oy = rem / OW, ox = rem % OW;

  const float ry = (float)((double)HH / (double)OH);
  const float rx = (float)((double)WW / (double)OW);
  float cy = fminf(fmaxf(((float)oy + 0.5f) * ry - 0.5f, 0.f), (float)(HH - 1));
  float cx = fminf(fmaxf(((float)ox + 0.5f) * rx - 0.5f, 0.f), (float)(WW - 1));
  int y0 = (int)floorf(cy);
  int x0 = (int)floorf(cx);
  int y1 = min(y0 + 1, HH - 1);
  int x1 = min(x0 + 1, WW - 1);
  float wy = cy - (float)y0;
  float wx = cx - (float)x0;

  float g00 = edge_at(image, vmask, b, y0, x0);
  float g01 = edge_at(image, vmask, b, y0, x1);
  float g10 = edge_at(image, vmask, b, y1, x0);
  float g11 = edge_at(image, vmask, b, y1, x1);
  float v = g00 * (1.f - wy) * (1.f - wx) + g01 * (1.f - wy) * wx +
            g10 * wy * (1.f - wx) + g11 * wy * wx;
  re[id] = v;
}

// ---------- K2: exact stable top-k by rank counting ----------
__global__ __launch_bounds__(256) void topk_kernel(const float* __restrict__ re,
                                                   int* __restrict__ coords) {
  const int b = blockIdx.x;
  const int t = threadIdx.x;
  __shared__ float e[OHW];
  for (int i = t; i < OHW; i += 256) e[i] = re[b * OHW + i];
  __syncthreads();
  for (int i = t; i < OHW; i += 256) {
    float v = e[i];
    int rank = 0;
    for (int j = 0; j < OHW; ++j) {
      float u = e[j];
      rank += (u > v) || (u == v && j < i);
    }
    if (rank < KTOP) {
      coords[(b * KTOP + rank) * 2 + 0] = (i / OW) * RESHAPE_I;
      coords[(b * KTOP + rank) * 2 + 1] = (i % OW) * RESHAPE_I;
    }
  }
}

// ---------- K3: per-patch SSI error ----------
__global__ __launch_bounds__(256) void patch_kernel(const float* __restrict__ inp,
                                                    const float* __restrict__ tgt,
                                                    const unsigned char* __restrict__ mask,
                                                    const int* __restrict__ coords,
                                                    float* __restrict__ ep, float* __restrict__ val) {
  const int bk = blockIdx.x;
  const int b = bk / KTOP;
  const int t = threadIdx.x;
  __shared__ float s_in[PATCH], s_tg[PATCH], s_mk[PATCH];
  __shared__ float red[256];
  __shared__ float sh_med_in, sh_med_tg;

  const int cy = coords[bk * 2 + 0];
  const int cx = coords[bk * 2 + 1];
  for (int i = t; i < PATCH; i += 256) {
    int dy = i / KS - PHW, dx = i % KS - PHW;
    int y = cy + dy, x = cx + dx;
    float mk = 0.f, vi = 0.f, vt = 0.f;
    if (y >= 0 && y < HH && x >= 0 && x < WW) {
      size_t off = (size_t)b * HWN + (size_t)y * WW + x;
      if (mask[off]) mk = 1.f;
      vi = inp[off];
      vt = tgt[off];
    }
    s_in[i] = vi; s_tg[i] = vt; s_mk[i] = mk;
  }
  if (t == 0) { sh_med_in = 0.f; sh_med_tg = 0.f; }
  __syncthreads();

  // n = count of masked
  float pn = 0.f;
  for (int i = t; i < PATCH; i += 256) pn += s_mk[i];
  float nf = breduce256(pn, red);
  int n = (int)(nf + 0.5f);
  int r = (n > 0) ? ((n - 1) >> 1) : 0;

  // exact lower-median of masked values by count-selection (value-identical to sort+index)
  for (int i = t; i < PATCH; i += 256) {
    if (s_mk[i] != 0.f) {
      float vi = s_in[i], wi = s_tg[i];
      int c1 = 0, e1 = 0, c2 = 0, e2 = 0;
      for (int j = 0; j < PATCH; ++j) {
        if (s_mk[j] != 0.f) {
          float vj = s_in[j], wj = s_tg[j];
          c1 += (vj < vi); e1 += (vj == vi);
          c2 += (wj < wi); e2 += (wj == wi);
        }
      }
      if (n > 0) {
        if (c1 <= r && r < c1 + e1) sh_med_in = vi;
        if (c2 <= r && r < c2 + e2) sh_med_tg = wi;
      }
    }
  }
  __syncthreads();
  float med_i = sh_med_in, med_t = sh_med_tg;

  // masked mean abs deviation
  float pi = 0.f, pt = 0.f;
  for (int i = t; i < PATCH; i += 256) {
    if (s_mk[i] != 0.f) {
      pi += fabsf(s_in[i] - med_i);
      pt += fabsf(s_tg[i] - med_t);
    }
  }
  float si = breduce256(pi, red) / fmaxf(nf, 1.f);
  float st = breduce256(pt, red) / fmaxf(nf, 1.f);
  si = fmaxf(si, EPSV);
  st = fmaxf(st, EPSV);

  // masked mean of max(|norm_in - norm_tg|, EPS)
  float pe = 0.f;
  for (int i = t; i < PATCH; i += 256) {
    if (s_mk[i] != 0.f) {
      float a = (s_in[i] - med_i) / si;
      float c = (s_tg[i] - med_t) / st;
      pe += fmaxf(fabsf(a - c), EPSV);
    }
  }
  float es = breduce256(pe, red);
  if (t == 0) {
    ep[bk] = sqrtf(fmaxf(es / fmaxf(nf, 1.f), EPSV));
    val[bk] = (n >= 4) ? 1.f : 0.f;
  }
}

// ---------- K4: e_patch[b] = masked mean of ep over valid ----------
__global__ __launch_bounds__(256) void preduce_kernel(const float* __restrict__ ep,
                                                      const float* __restrict__ val,
                                                      float* __restrict__ e_patch) {
  const int b = blockIdx.x;
  const int t = threadIdx.x;
  __shared__ float red[256];
  float se = 0.f, sv = 0.f;
  for (int i = t; i < KTOP; i += 256) {
    float v = val[b * KTOP + i];
    se += ep[b * KTOP + i] * v;
    sv += v;
  }
  float tse = breduce256(se, red);
  float tsv = breduce256(sv, red);
  if (t == 0) e_patch[b] = tse / fmaxf(tsv, 1.f);
}

// ---------- K5: global exact median (radix select) + scale, per (batch, signal) ----------
__global__ __launch_bounds__(1024) void gmed_kernel(const float* __restrict__ inp,
                                                    const float* __restrict__ tgt,
                                                    const unsigned char* __restrict__ mask,
                                                    float* __restrict__ gstats,
                                                    float* __restrict__ nvals) {
  const int b = blockIdx.x >> 1, s = blockIdx.x & 1;
  const float* x = (s == 0 ? inp : tgt) + (size_t)b * HWN;
  const unsigned char* m = mask + (size_t)b * HWN;
  __shared__ unsigned int hist[1024];
  __shared__ float red[1024];
  __shared__ unsigned int sh_prefix;
  __shared__ int sh_r, sh_n;
  __shared__ float sh_med;
  const int t = threadIdx.x;

  // passes 0..2: 10-bit digits at shifts 22, 12, 2
  for (int p = 0; p < 3; ++p) {
    hist[t] = 0;
    __syncthreads();
    const int shift = 22 - 10 * p;
    unsigned int pref = (p == 0) ? 0u : sh_prefix;
    bool run = (p == 0) || (sh_r >= 0);
    if (run) {
      for (int i = t; i < HWN; i += 1024) {
        if (m[i]) {
          unsigned int key = fkey(x[i]);
          if (p == 0 || (key >> (shift + 10)) == pref)
            atomicAdd(&hist[(key >> shift) & 1023u], 1u);
        }
      }
    }
    __syncthreads();
    if (t == 0) {
      if (p == 0) {
        unsigned int tot = 0;
        for (int i = 0; i < 1024; ++i) tot += hist[i];
        sh_n = (int)tot;
        sh_r = (tot > 0) ? (int)((tot - 1) >> 1) : -1;
        sh_prefix = 0;
      }
      if (sh_r >= 0) {
        unsigned int rr = (unsigned int)sh_r, cum = 0;
        int bin = 0;
        for (; bin < 1024; ++bin) {
          unsigned int h = hist[bin];
          if (cum + h > rr) break;
          cum += h;
        }
        sh_r = (int)(rr - cum);
        sh_prefix = (sh_prefix << 10) | (unsigned int)bin;
      }
    }
    __syncthreads();
  }

  // final 2-bit pass
  if (t < 4) hist[t] = 0;
  __syncthreads();
  unsigned int pref30 = sh_prefix;
  if (sh_r >= 0) {
    for (int i = t; i < HWN; i += 1024) {
      if (m[i]) {
        unsigned int key = fkey(x[i]);
        if ((key >> 2) == pref30) atomicAdd(&hist[key & 3u], 1u);
      }
    }
  }
  __syncthreads();
  if (t == 0) {
    if (sh_r >= 0) {
      unsigned int rr = (unsigned int)sh_r, cum = 0;
      int bin = 0;
      for (; bin < 4; ++bin) {
        unsigned int h = hist[bin];
        if (cum + h > rr) break;
        cum += h;
      }
      sh_med = fkey_inv((pref30 << 2) | (unsigned int)bin);
    } else {
      sh_med = 0.f;
    }
  }
  __syncthreads();
  float med = sh_med;

  // masked mean abs deviation
  float part = 0.f;
  for (int i = t; i < HWN; i += 1024) {
    if (m[i]) part += fabsf(x[i] - med);
  }
  red[t] = part;
  __syncthreads();
  for (int sred = 512; sred > 0; sred >>= 1) {
    if (t < sred) red[t] += red[t + sred];
    __syncthreads();
  }
  if (t == 0) {
    float scale = red[0] / fmaxf((float)sh_n, 1.f);
    gstats[(b * 2 + s) * 2 + 0] = med;
    gstats[(b * 2 + s) * 2 + 1] = scale;
    if (s == 0) nvals[b] = (float)sh_n;
  }
}

// ---------- K6: global error + final combine ----------
__global__ __launch_bounds__(1024) void gerr_kernel(const float* __restrict__ inp,
                                                    const float* __restrict__ tgt,
                                                    const unsigned char* __restrict__ mask,
                                                    const float* __restrict__ gstats,
                                                    const float* __restrict__ nvals,
                                                    const float* __restrict__ e_patch,
                                                    float* __restrict__ out) {
  const int b = blockIdx.x;
  const float* xi = inp + (size_t)b * HWN;
  const float* xt = tgt + (size_t)b * HWN;
  const unsigned char* m = mask + (size_t)b * HWN;
  __shared__ float red[1024];
  const int t = threadIdx.x;
  const float med_i = gstats[(b * 2 + 0) * 2 + 0];
  const float sc_i = fmaxf(gstats[(b * 2 + 0) * 2 + 1], EPSV);
  const float med_t = gstats[(b * 2 + 1) * 2 + 0];
  const float sc_t = fmaxf(gstats[(b * 2 + 1) * 2 + 1], EPSV);
  float part = 0.f;
  for (int i = t; i < HWN; i += 1024) {
    if (m[i]) {
      float a = (xi[i] - med_i) / sc_i;
      float c = (xt[i] - med_t) / sc_t;
      part += fmaxf(fabsf(a - c), EPSV);
    }
  }
  red[t] = part;
  __syncthreads();
  for (int sred = 512; sred > 0; sred >>= 1) {
    if (t < sred) red[t] += red[t + sred];
    __syncthreads();
  }
  if (t == 0) {
    float n = nvals[b];
    float eg = sqrtf(fmaxf(red[0] / fmaxf(n, 1.f), EPSV));
    out[b] = 0.5f * (e_patch[b] + eg);
  }
}

extern "C" void kernel_launch(void* const* d_in, const int* in_sizes, int n_in,
                              void* d_out, int out_size, void* d_ws, size_t ws_size,
                              hipStream_t stream) {
  const float* inp = (const float*)d_in[0];
  const float* tgt = (const float*)d_in[1];
  const unsigned char* mask = (const unsigned char*)d_in[2];   // jax bool -> 1 byte
  const float* image = (const float*)d_in[3];
  const unsigned char* vmask = (const unsigned char*)d_in[4];  // jax bool -> 1 byte
  float* out = (float*)d_out;

  float* ws = (float*)d_ws;
  float* re = ws;                              // BB*OHW
  int* coords = (int*)(ws + BB * OHW);         // BB*KTOP*2 ints
  float* ep = ws + BB * OHW + BB * KTOP * 2;   // BB*KTOP
  float* val = ep + BB * KTOP;                 // BB*KTOP
  float* e_patch = val + BB * KTOP;            // BB
  float* gstats = e_patch + BB;                // BB*2*2 (med, scale per signal)
  float* nvals = gstats + BB * 4;              // BB

  edge_resize_kernel<<<(BB * OHW + 255) / 256, 256, 0, stream>>>(image, vmask, re);
  topk_kernel<<<BB, 256, 0, stream>>>(re, coords);
  patch_kernel<<<BB * KTOP, 256, 0, stream>>>(inp, tgt, mask, coords, ep, val);
  preduce_kernel<<<BB, 256, 0, stream>>>(ep, val, e_patch);
  gmed_kernel<<<BB * 2, 1024, 0, stream>>>(inp, tgt, mask, gstats, nvals);
  gerr_kernel<<<BB, 1024, 0, stream>>>(inp, tgt, mask, gstats, nvals, e_patch, out);
}

// Round 2
// 1475.087 us; speedup vs baseline: 1.5650x; 1.5650x over previous
//
#include <hip/hip_runtime.h>
#include <math.h>

// Problem constants (fixed by setup_inputs: B=32, H=480, W=640)
#define BB 32
#define HH 480
#define WW 640
#define HWN (HH * WW)
#define OH 34            // H // RESHAPE
#define OW 45            // W // RESHAPE
#define OHW (OH * OW)    // 1530
#define KTOP 153         // max(int(0.1*oh*ow), 10)
#define KS 25            // kernel size (odd)
#define PHW 12           // half kernel
#define PATCH (KS * KS)  // 625
#define RESHAPE_I 14
#define EPSV 1e-5f

// global-median machinery
#define GBINS 16384      // top-14 bits of monotone key
#define GSHIFT 18        // 32 - 14
#define NSLICE 16        // WGs per (b,s) for data passes
#define CAP 16384        // candidate cap per (b,s); worst bin for this data ~7k

// ---------- monotone float <-> uint key ----------
__device__ __forceinline__ unsigned int fkey(float f) {
  unsigned int u = __float_as_uint(f);
  return (u & 0x80000000u) ? ~u : (u | 0x80000000u);
}
__device__ __forceinline__ float fkey_inv(unsigned int k) {
  unsigned int u = (k & 0x80000000u) ? (k & 0x7FFFFFFFu) : ~k;
  return __uint_as_float(u);
}

// ---------- 256-thread block reduce ----------
__device__ __forceinline__ float breduce256(float v, float* red) {
  const int t = threadIdx.x;
  __syncthreads();
  red[t] = v;
  __syncthreads();
  for (int s2 = 128; s2 > 0; s2 >>= 1) {
    if (t < s2) red[t] += red[t + s2];
    __syncthreads();
  }
  float r = red[0];
  __syncthreads();
  return r;
}

// ---------- edge value at (b, y, x): sobel + erode(validity) + border mask ----------
__device__ float edge_at(const float* __restrict__ image, const unsigned char* __restrict__ vmask,
                         int b, int y, int x) {
  if (y < 3 || y >= HH - 3 || x < 3 || x >= WW - 3) return 0.f;
  const unsigned char* vm = vmask + (size_t)b * HWN;
  #pragma unroll
  for (int dy = -1; dy <= 1; ++dy) {
    #pragma unroll
    for (int dx = -1; dx <= 1; ++dx) {
      if (!vm[(size_t)(y + dy) * WW + (x + dx)]) return 0.f;
    }
  }
  const float* img = image + (size_t)b * 3 * HWN;
  float sx2 = 0.f, sy2 = 0.f;
  #pragma unroll
  for (int c = 0; c < 3; ++c) {
    const float* p = img + (size_t)c * HWN + (size_t)y * WW + x;
    float a00 = p[-WW - 1], a01 = p[-WW], a02 = p[-WW + 1];
    float a10 = p[-1],                    a12 = p[1];
    float a20 = p[WW - 1],  a21 = p[WW],  a22 = p[WW + 1];
    float gx = (-a00 + a02 + -2.f * a10 + 2.f * a12 + -a20 + a22) / 8.f;
    float gy = (-a00 + -2.f * a01 + -a02 + a20 + 2.f * a21 + a22) / 8.f;
    sx2 += gx * gx;
    sy2 += gy * gy;
  }
  float gxm = sqrtf(sx2 / 3.f);
  float gym = sqrtf(sy2 / 3.f);
  return sqrtf(gxm * gxm + gym * gym);
}

// ---------- K1: fused edge + bilinear resize ----------
__global__ __launch_bounds__(256) void edge_resize_kernel(const float* __restrict__ image,
                                                          const unsigned char* __restrict__ vmask,
                                                          float* __restrict__ re) {
  int id = blockIdx.x * 256 + threadIdx.x;
  if (id >= BB * OHW) return;
  int b = id / OHW;
  int rem = id % OHW;
  int oy = rem / OW, ox = rem % OW;

  const float ry = (float)((double)HH / (double)OH);
  const float rx = (float)((double)WW / (double)OW);
  float cy = fminf(fmaxf(((float)oy + 0.5f) * ry - 0.5f, 0.f), (float)(HH - 1));
  float cx = fminf(fmaxf(((float)ox + 0.5f) * rx - 0.5f, 0.f), (float)(WW - 1));
  int y0 = (int)floorf(cy);
  int x0 = (int)floorf(cx);
  int y1 = min(y0 + 1, HH - 1);
  int x1 = min(x0 + 1, WW - 1);
  float wy = cy - (float)y0;
  float wx = cx - (float)x0;

  float g00 = edge_at(image, vmask, b, y0, x0);
  float g01 = edge_at(image, vmask, b, y0, x1);
  float g10 = edge_at(image, vmask, b, y1, x0);
  float g11 = edge_at(image, vmask, b, y1, x1);
  re[id] = g00 * (1.f - wy) * (1.f - wx) + g01 * (1.f - wy) * wx +
           g10 * wy * (1.f - wx) + g11 * wy * wx;
}

// ---------- K2: exact stable top-k by rank counting ----------
__global__ __launch_bounds__(256) void topk_kernel(const float* __restrict__ re,
                                                   int* __restrict__ coords) {
  const int b = blockIdx.x;
  const int t = threadIdx.x;
  __shared__ float e[OHW];
  for (int i = t; i < OHW; i += 256) e[i] = re[b * OHW + i];
  __syncthreads();
  for (int i = t; i < OHW; i += 256) {
    float v = e[i];
    int rank = 0;
    for (int j = 0; j < OHW; ++j) {
      float u = e[j];
      rank += (u > v) || (u == v && j < i);
    }
    if (rank < KTOP) {
      coords[(b * KTOP + rank) * 2 + 0] = (i / OW) * RESHAPE_I;
      coords[(b * KTOP + rank) * 2 + 1] = (i % OW) * RESHAPE_I;
    }
  }
}

// ---------- K3: per-patch SSI error ----------
__global__ __launch_bounds__(256) void patch_kernel(const float* __restrict__ inp,
                                                    const float* __restrict__ tgt,
                                                    const unsigned char* __restrict__ mask,
                                                    const int* __restrict__ coords,
                                                    float* __restrict__ ep, float* __restrict__ val) {
  const int bk = blockIdx.x;
  const int b = bk / KTOP;
  const int t = threadIdx.x;
  __shared__ float s_in[PATCH], s_tg[PATCH], s_mk[PATCH];
  __shared__ float red[256];
  __shared__ float sh_med_in, sh_med_tg;

  const int cy = coords[bk * 2 + 0];
  const int cx = coords[bk * 2 + 1];
  for (int i = t; i < PATCH; i += 256) {
    int dy = i / KS - PHW, dx = i % KS - PHW;
    int y = cy + dy, x = cx + dx;
    float mk = 0.f, vi = 0.f, vt = 0.f;
    if (y >= 0 && y < HH && x >= 0 && x < WW) {
      size_t off = (size_t)b * HWN + (size_t)y * WW + x;
      if (mask[off]) mk = 1.f;
      vi = inp[off];
      vt = tgt[off];
    }
    s_in[i] = vi; s_tg[i] = vt; s_mk[i] = mk;
  }
  if (t == 0) { sh_med_in = 0.f; sh_med_tg = 0.f; }
  __syncthreads();

  float pn = 0.f;
  for (int i = t; i < PATCH; i += 256) pn += s_mk[i];
  float nf = breduce256(pn, red);
  int n = (int)(nf + 0.5f);
  int r = (n > 0) ? ((n - 1) >> 1) : 0;

  for (int i = t; i < PATCH; i += 256) {
    if (s_mk[i] != 0.f) {
      float vi = s_in[i], wi = s_tg[i];
      int c1 = 0, e1 = 0, c2 = 0, e2 = 0;
      for (int j = 0; j < PATCH; ++j) {
        if (s_mk[j] != 0.f) {
          float vj = s_in[j], wj = s_tg[j];
          c1 += (vj < vi); e1 += (vj == vi);
          c2 += (wj < wi); e2 += (wj == wi);
        }
      }
      if (n > 0) {
        if (c1 <= r && r < c1 + e1) sh_med_in = vi;
        if (c2 <= r && r < c2 + e2) sh_med_tg = wi;
      }
    }
  }
  __syncthreads();
  float med_i = sh_med_in, med_t = sh_med_tg;

  float pi = 0.f, pt = 0.f;
  for (int i = t; i < PATCH; i += 256) {
    if (s_mk[i] != 0.f) {
      pi += fabsf(s_in[i] - med_i);
      pt += fabsf(s_tg[i] - med_t);
    }
  }
  float si = breduce256(pi, red) / fmaxf(nf, 1.f);
  float st = breduce256(pt, red) / fmaxf(nf, 1.f);
  si = fmaxf(si, EPSV);
  st = fmaxf(st, EPSV);

  float pe = 0.f;
  for (int i = t; i < PATCH; i += 256) {
    if (s_mk[i] != 0.f) {
      float a = (s_in[i] - med_i) / si;
      float c = (s_tg[i] - med_t) / st;
      pe += fmaxf(fabsf(a - c), EPSV);
    }
  }
  float es = breduce256(pe, red);
  if (t == 0) {
    ep[bk] = sqrtf(fmaxf(es / fmaxf(nf, 1.f), EPSV));
    val[bk] = (n >= 4) ? 1.f : 0.f;
  }
}

// ---------- K4: e_patch[b] ----------
__global__ __launch_bounds__(256) void preduce_kernel(const float* __restrict__ ep,
                                                      const float* __restrict__ val,
                                                      float* __restrict__ e_patch) {
  const int b = blockIdx.x;
  const int t = threadIdx.x;
  __shared__ float red[256];
  float se = 0.f, sv = 0.f;
  for (int i = t; i < KTOP; i += 256) {
    float v = val[b * KTOP + i];
    se += ep[b * KTOP + i] * v;
    sv += v;
  }
  float tse = breduce256(se, red);
  float tsv = breduce256(sv, red);
  if (t == 0) e_patch[b] = tse / fmaxf(tsv, 1.f);
}

// ---------- K5a: wide histogram of top-14 key bits ----------
// grid: (BB*2) * NSLICE; block 256. LDS 64KB hist.
__global__ __launch_bounds__(256) void ghist_kernel(const float* __restrict__ inp,
                                                    const float* __restrict__ tgt,
                                                    const unsigned char* __restrict__ mask,
                                                    unsigned int* __restrict__ ghist) {
  const int bs = blockIdx.x / NSLICE;
  const int sl = blockIdx.x % NSLICE;
  const int b = bs >> 1, s = bs & 1;
  const float* x = (s == 0 ? inp : tgt) + (size_t)b * HWN;
  const unsigned char* m = mask + (size_t)b * HWN;
  __shared__ unsigned int hist[GBINS];
  const int t = threadIdx.x;
  for (int i = t; i < GBINS; i += 256) hist[i] = 0;
  __syncthreads();
  const int per = HWN / NSLICE;  // 19200
  const int i0 = sl * per;
  for (int i = i0 + t; i < i0 + per; i += 256) {
    if (m[i]) atomicAdd(&hist[fkey(x[i]) >> GSHIFT], 1u);
  }
  __syncthreads();
  unsigned int* gh = ghist + (size_t)bs * GBINS;
  for (int i = t; i < GBINS; i += 256) {
    unsigned int h = hist[i];
    if (h) atomicAdd(&gh[i], h);
  }
}

// ---------- K5b: find median bin, ranks, n_below ----------
// grid: BB*2; block 256. sel[bs] = {bstar, r2, n, n_below}
__global__ __launch_bounds__(256) void gsel_kernel(const unsigned int* __restrict__ ghist,
                                                   int* __restrict__ sel) {
  const int bs = blockIdx.x;
  const int t = threadIdx.x;
  const unsigned int* gh = ghist + (size_t)bs * GBINS;
  __shared__ unsigned int part[256];
  unsigned int p = 0;
  const int per = GBINS / 256;  // 64
  for (int i = 0; i < per; ++i) p += gh[t * per + i];
  part[t] = p;
  __syncthreads();
  if (t == 0) {
    unsigned int n = 0;
    for (int i = 0; i < 256; ++i) n += part[i];
    int bstar = -1, r2 = 0;
    unsigned int nbelow = 0;
    if (n > 0) {
      unsigned int r = (n - 1) >> 1;
      unsigned int cum = 0;
      int seg = 0;
      for (; seg < 256; ++seg) {
        if (cum + part[seg] > r) break;
        cum += part[seg];
      }
      int bin = seg * per;
      for (;; ++bin) {
        unsigned int h = gh[bin];
        if (cum + h > r) break;
        cum += h;
      }
      bstar = bin;
      r2 = (int)(r - cum);
      nbelow = cum;
    }
    sel[bs * 4 + 0] = bstar;
    sel[bs * 4 + 1] = r2;
    sel[bs * 4 + 2] = (int)n;
    sel[bs * 4 + 3] = (int)nbelow;
  }
}

// ---------- K5c: collect candidates + below/above sums ----------
__global__ __launch_bounds__(256) void gcollect_kernel(const float* __restrict__ inp,
                                                       const float* __restrict__ tgt,
                                                       const unsigned char* __restrict__ mask,
                                                       const int* __restrict__ sel,
                                                       float* __restrict__ cand,
                                                       unsigned int* __restrict__ ccount,
                                                       float* __restrict__ sbelow,
                                                       float* __restrict__ sabove) {
  const int bs = blockIdx.x / NSLICE;
  const int sl = blockIdx.x % NSLICE;
  const int b = bs >> 1, s = bs & 1;
  const float* x = (s == 0 ? inp : tgt) + (size_t)b * HWN;
  const unsigned char* m = mask + (size_t)b * HWN;
  const int bstar = sel[bs * 4 + 0];
  __shared__ float red[256];
  const int t = threadIdx.x;
  const int per = HWN / NSLICE;
  const int i0 = sl * per;
  float sb = 0.f, sa = 0.f;
  if (bstar >= 0) {
    float* cd = cand + (size_t)bs * CAP;
    for (int i = i0 + t; i < i0 + per; i += 256) {
      if (m[i]) {
        float v = x[i];
        int bin = (int)(fkey(v) >> GSHIFT);
        if (bin < bstar) sb += v;
        else if (bin > bstar) sa += v;
        else {
          unsigned int pos = atomicAdd(&ccount[bs], 1u);
          if (pos < CAP) cd[pos] = v;
        }
      }
    }
  }
  float tsb = breduce256(sb, red);
  float tsa = breduce256(sa, red);
  if (t == 0) {
    atomicAdd(&sbelow[bs], tsb);
    atomicAdd(&sabove[bs], tsa);
  }
}

// ---------- K5d: exact select among candidates + scale ----------
// grid BB*2, block 256. Two 9-bit radix passes over low 18 key bits.
__global__ __launch_bounds__(256) void gfinal_kernel(const float* __restrict__ cand,
                                                     const unsigned int* __restrict__ ccount,
                                                     const int* __restrict__ sel,
                                                     const float* __restrict__ sbelow,
                                                     const float* __restrict__ sabove,
                                                     float* __restrict__ gstats,
                                                     float* __restrict__ nvals) {
  const int bs = blockIdx.x;
  const int t = threadIdx.x;
  const int bstar = sel[bs * 4 + 0];
  const int r2 = sel[bs * 4 + 1];
  const int n = sel[bs * 4 + 2];
  const int nbelow = sel[bs * 4 + 3];
  __shared__ unsigned int hist[512];
  __shared__ float red[256];
  __shared__ int sh_bin1, sh_r3;
  const float* cd = cand + (size_t)bs * CAP;
  int c = (int)min(ccount[bs], (unsigned int)CAP);
  if (bstar < 0) {
    if (t == 0) {
      gstats[bs * 2 + 0] = 0.f;
      gstats[bs * 2 + 1] = 0.f;
      if ((bs & 1) == 0) nvals[bs >> 1] = 0.f;
    }
    return;
  }

  // pass 1: bits [17:9]
  for (int i = t; i < 512; i += 256) hist[i] = 0;
  __syncthreads();
  for (int i = t; i < c; i += 256)
    atomicAdd(&hist[(fkey(cd[i]) >> 9) & 511u], 1u);
  __syncthreads();
  if (t == 0) {
    unsigned int rr = (unsigned int)r2, cum = 0;
    int bin = 0;
    for (; bin < 512; ++bin) {
      unsigned int h = hist[bin];
      if (cum + h > rr) break;
      cum += h;
    }
    sh_bin1 = bin;
    sh_r3 = (int)(rr - cum);
  }
  __syncthreads();
  const int bin1 = sh_bin1;
  const int r3 = sh_r3;

  // pass 2: bits [8:0]
  for (int i = t; i < 512; i += 256) hist[i] = 0;
  __syncthreads();
  for (int i = t; i < c; i += 256) {
    unsigned int key = fkey(cd[i]);
    if (((key >> 9) & 511u) == (unsigned int)bin1)
      atomicAdd(&hist[key & 511u], 1u);
  }
  __syncthreads();
  __shared__ float sh_med;
  if (t == 0) {
    unsigned int rr = (unsigned int)r3, cum = 0;
    int bin = 0;
    for (; bin < 512; ++bin) {
      unsigned int h = hist[bin];
      if (cum + h > rr) break;
      cum += h;
    }
    unsigned int key = ((unsigned int)bstar << GSHIFT) |
                       ((unsigned int)bin1 << 9) | (unsigned int)bin;
    sh_med = fkey_inv(key);
  }
  __syncthreads();
  const float med = sh_med;

  // sum |cand - med| over in-bin candidates
  float ps = 0.f;
  for (int i = t; i < c; i += 256) ps += fabsf(cd[i] - med);
  float scand = breduce256(ps, red);
  if (t == 0) {
    float nb = (float)nbelow;
    float na = (float)(n - nbelow - c);
    float num = (nb * med - sbelow[bs]) + (sabove[bs] - na * med) + scand;
    gstats[bs * 2 + 0] = med;
    gstats[bs * 2 + 1] = num / fmaxf((float)n, 1.f);
    if ((bs & 1) == 0) nvals[bs >> 1] = (float)n;
  }
}

// ---------- K6a: global error partial sums ----------
__global__ __launch_bounds__(256) void gerr_kernel(const float* __restrict__ inp,
                                                   const float* __restrict__ tgt,
                                                   const unsigned char* __restrict__ mask,
                                                   const float* __restrict__ gstats,
                                                   float* __restrict__ gacc) {
  const int b = blockIdx.x / NSLICE;
  const int sl = blockIdx.x % NSLICE;
  const float* xi = inp + (size_t)b * HWN;
  const float* xt = tgt + (size_t)b * HWN;
  const unsigned char* m = mask + (size_t)b * HWN;
  __shared__ float red[256];
  const int t = threadIdx.x;
  const float med_i = gstats[(b * 2 + 0) * 2 + 0];
  const float sc_i = fmaxf(gstats[(b * 2 + 0) * 2 + 1], EPSV);
  const float med_t = gstats[(b * 2 + 1) * 2 + 0];
  const float sc_t = fmaxf(gstats[(b * 2 + 1) * 2 + 1], EPSV);
  const int per = HWN / NSLICE;
  const int i0 = sl * per;
  float part = 0.f;
  for (int i = i0 + t; i < i0 + per; i += 256) {
    if (m[i]) {
      float a = (xi[i] - med_i) / sc_i;
      float cc = (xt[i] - med_t) / sc_t;
      part += fmaxf(fabsf(a - cc), EPSV);
    }
  }
  float tp = breduce256(part, red);
  if (t == 0) atomicAdd(&gacc[b], tp);
}

// ---------- K6b: combine ----------
__global__ __launch_bounds__(64) void final_kernel(const float* __restrict__ gacc,
                                                   const float* __restrict__ nvals,
                                                   const float* __restrict__ e_patch,
                                                   float* __restrict__ out) {
  const int b = threadIdx.x;
  if (b < BB) {
    float n = nvals[b];
    float eg = sqrtf(fmaxf(gacc[b] / fmaxf(n, 1.f), EPSV));
    out[b] = 0.5f * (e_patch[b] + eg);
  }
}

extern "C" void kernel_launch(void* const* d_in, const int* in_sizes, int n_in,
                              void* d_out, int out_size, void* d_ws, size_t ws_size,
                              hipStream_t stream) {
  const float* inp = (const float*)d_in[0];
  const float* tgt = (const float*)d_in[1];
  const unsigned char* mask = (const unsigned char*)d_in[2];   // jax bool -> 1 byte
  const float* image = (const float*)d_in[3];
  const unsigned char* vmask = (const unsigned char*)d_in[4];  // jax bool -> 1 byte
  float* out = (float*)d_out;

  float* ws = (float*)d_ws;
  // read/write scratch (no zeroing needed)
  float* re = ws;                                   // 48960
  int* coords = (int*)(ws + 48960);                 // 9792
  float* ep = ws + 48960 + 9792;                    // 4896
  float* val = ep + 4896;                           // 4896
  float* e_patch = val + 4896;                      // 32
  float* gstats = e_patch + 32;                     // 128
  float* nvals = gstats + 128;                      // 32
  int* sel = (int*)(nvals + 32);                    // 256
  float* cand = (float*)(sel + 256);                // 64*CAP = 1048576
  // zeroed region (one contiguous memset)
  unsigned int* ghist = (unsigned int*)(cand + (size_t)64 * CAP);  // 64*GBINS
  unsigned int* ccount = ghist + (size_t)64 * GBINS;               // 64
  float* sbelow = (float*)(ccount + 64);                           // 64
  float* sabove = sbelow + 64;                                     // 64
  float* gacc = sabove + 64;                                       // 32
  size_t zero_bytes = ((size_t)64 * GBINS + 64 + 64 + 64 + 32) * 4;
  hipMemsetAsync(ghist, 0, zero_bytes, stream);

  edge_resize_kernel<<<(BB * OHW + 255) / 256, 256, 0, stream>>>(image, vmask, re);
  topk_kernel<<<BB, 256, 0, stream>>>(re, coords);
  patch_kernel<<<BB * KTOP, 256, 0, stream>>>(inp, tgt, mask, coords, ep, val);
  preduce_kernel<<<BB, 256, 0, stream>>>(ep, val, e_patch);
  ghist_kernel<<<BB * 2 * NSLICE, 256, 0, stream>>>(inp, tgt, mask, ghist);
  gsel_kernel<<<BB * 2, 256, 0, stream>>>(ghist, sel);
  gcollect_kernel<<<BB * 2 * NSLICE, 256, 0, stream>>>(inp, tgt, mask, sel, cand, ccount, sbelow, sabove);
  gfinal_kernel<<<BB * 2, 256, 0, stream>>>(cand, ccount, sel, sbelow, sabove, gstats, nvals);
  gerr_kernel<<<BB * NSLICE, 256, 0, stream>>>(inp, tgt, mask, gstats, gacc);
  final_kernel<<<1, 64, 0, stream>>>(gacc, nvals, e_patch, out);
}

// Round 3
// 974.683 us; speedup vs baseline: 2.3684x; 1.5134x over previous
//
#include <hip/hip_runtime.h>
#include <math.h>

// Problem constants (fixed by setup_inputs: B=32, H=480, W=640)
#define BB 32
#define HH 480
#define WW 640
#define HWN (HH * WW)
#define OH 34            // H // RESHAPE
#define OW 45            // W // RESHAPE
#define OHW (OH * OW)    // 1530
#define KTOP 153         // max(int(0.1*oh*ow), 10)
#define KS 25            // kernel size (odd)
#define PHW 12           // half kernel
#define PATCH (KS * KS)  // 625
#define RESHAPE_I 14
#define EPSV 1e-5f

// global-median machinery
#define GBINS 16384      // top-14 bits of monotone key
#define GSHIFT 18        // 32 - 14
#define NSLICE 16        // WGs per (b,s) for data passes
#define CAP 16384        // candidate cap per (b,s)

// ---------- monotone float <-> uint key ----------
__device__ __forceinline__ unsigned int fkey(float f) {
  unsigned int u = __float_as_uint(f);
  return (u & 0x80000000u) ? ~u : (u | 0x80000000u);
}
__device__ __forceinline__ float fkey_inv(unsigned int k) {
  unsigned int u = (k & 0x80000000u) ? (k & 0x7FFFFFFFu) : ~k;
  return __uint_as_float(u);
}

// ---------- 256-thread block reduce (single) ----------
__device__ __forceinline__ float breduce256(float v, float* red) {
  const int t = threadIdx.x;
  __syncthreads();
  red[t] = v;
  __syncthreads();
  for (int s2 = 128; s2 > 0; s2 >>= 1) {
    if (t < s2) red[t] += red[t + s2];
    __syncthreads();
  }
  float r = red[0];
  __syncthreads();
  return r;
}

// ---------- 256-thread block reduce (pair) ----------
__device__ __forceinline__ float2 breduce256x2(float a, float b, float* red) {
  const int t = threadIdx.x;
  __syncthreads();
  red[t] = a;
  red[256 + t] = b;
  __syncthreads();
  for (int s2 = 128; s2 > 0; s2 >>= 1) {
    if (t < s2) {
      red[t] += red[t + s2];
      red[256 + t] += red[256 + t + s2];
    }
    __syncthreads();
  }
  float2 r = make_float2(red[0], red[256]);
  __syncthreads();
  return r;
}

// ---------- edge value at (b, y, x): sobel + erode(validity) + border mask ----------
__device__ float edge_at(const float* __restrict__ image, const unsigned char* __restrict__ vmask,
                         int b, int y, int x) {
  if (y < 3 || y >= HH - 3 || x < 3 || x >= WW - 3) return 0.f;
  const unsigned char* vm = vmask + (size_t)b * HWN;
  #pragma unroll
  for (int dy = -1; dy <= 1; ++dy) {
    #pragma unroll
    for (int dx = -1; dx <= 1; ++dx) {
      if (!vm[(size_t)(y + dy) * WW + (x + dx)]) return 0.f;
    }
  }
  const float* img = image + (size_t)b * 3 * HWN;
  float sx2 = 0.f, sy2 = 0.f;
  #pragma unroll
  for (int c = 0; c < 3; ++c) {
    const float* p = img + (size_t)c * HWN + (size_t)y * WW + x;
    float a00 = p[-WW - 1], a01 = p[-WW], a02 = p[-WW + 1];
    float a10 = p[-1],                    a12 = p[1];
    float a20 = p[WW - 1],  a21 = p[WW],  a22 = p[WW + 1];
    float gx = (-a00 + a02 + -2.f * a10 + 2.f * a12 + -a20 + a22) / 8.f;
    float gy = (-a00 + -2.f * a01 + -a02 + a20 + 2.f * a21 + a22) / 8.f;
    sx2 += gx * gx;
    sy2 += gy * gy;
  }
  float gxm = sqrtf(sx2 / 3.f);
  float gym = sqrtf(sy2 / 3.f);
  return sqrtf(gxm * gxm + gym * gym);
}

// ---------- K1: fused edge + bilinear resize ----------
__global__ __launch_bounds__(256) void edge_resize_kernel(const float* __restrict__ image,
                                                          const unsigned char* __restrict__ vmask,
                                                          float* __restrict__ re) {
  int id = blockIdx.x * 256 + threadIdx.x;
  if (id >= BB * OHW) return;
  int b = id / OHW;
  int rem = id % OHW;
  int oy = rem / OW, ox = rem % OW;

  const float ry = (float)((double)HH / (double)OH);
  const float rx = (float)((double)WW / (double)OW);
  float cy = fminf(fmaxf(((float)oy + 0.5f) * ry - 0.5f, 0.f), (float)(HH - 1));
  float cx = fminf(fmaxf(((float)ox + 0.5f) * rx - 0.5f, 0.f), (float)(WW - 1));
  int y0 = (int)floorf(cy);
  int x0 = (int)floorf(cx);
  int y1 = min(y0 + 1, HH - 1);
  int x1 = min(x0 + 1, WW - 1);
  float wy = cy - (float)y0;
  float wx = cx - (float)x0;

  float g00 = edge_at(image, vmask, b, y0, x0);
  float g01 = edge_at(image, vmask, b, y0, x1);
  float g10 = edge_at(image, vmask, b, y1, x0);
  float g11 = edge_at(image, vmask, b, y1, x1);
  re[id] = g00 * (1.f - wy) * (1.f - wx) + g01 * (1.f - wy) * wx +
           g10 * wy * (1.f - wx) + g11 * wy * wx;
}

// ---------- K2: exact stable top-k by rank counting ----------
__global__ __launch_bounds__(256) void topk_kernel(const float* __restrict__ re,
                                                   int* __restrict__ coords) {
  const int b = blockIdx.x;
  const int t = threadIdx.x;
  __shared__ float e[OHW];
  for (int i = t; i < OHW; i += 256) e[i] = re[b * OHW + i];
  __syncthreads();
  for (int i = t; i < OHW; i += 256) {
    float v = e[i];
    int rank = 0;
    for (int j = 0; j < OHW; ++j) {
      float u = e[j];
      rank += (u > v) || (u == v && j < i);
    }
    if (rank < KTOP) {
      coords[(b * KTOP + rank) * 2 + 0] = (i / OW) * RESHAPE_I;
      coords[(b * KTOP + rank) * 2 + 1] = (i % OW) * RESHAPE_I;
    }
  }
}

// ---------- K3: per-patch SSI error via exact LDS radix select ----------
// One WG per patch. 3 elements/thread live in registers. Median = 4-pass
// 8-bit radix select over monotone keys (bit-exact vs sort[r]).
__global__ __launch_bounds__(256) void patch_kernel(const float* __restrict__ inp,
                                                    const float* __restrict__ tgt,
                                                    const unsigned char* __restrict__ mask,
                                                    const int* __restrict__ coords,
                                                    float* __restrict__ ep, float* __restrict__ val) {
  const int bk = blockIdx.x;
  const int b = bk / KTOP;
  const int t = threadIdx.x;
  __shared__ unsigned int hist[512];   // [0:256) in, [256:512) tg
  __shared__ unsigned int scan[512];
  __shared__ float redf[512];
  __shared__ unsigned int sh_pref[2];
  __shared__ int sh_rank[2];

  const int cy = coords[bk * 2 + 0];
  const int cx = coords[bk * 2 + 1];

  float v_in[3], v_tg[3], mk[3];
  unsigned int k_in[3], k_tg[3];
  #pragma unroll
  for (int q = 0; q < 3; ++q) {
    int i = t + q * 256;
    float mkv = 0.f, vi = 0.f, vt = 0.f;
    if (i < PATCH) {
      int dy = i / KS - PHW, dx = i % KS - PHW;
      int y = cy + dy, x = cx + dx;
      if (y >= 0 && y < HH && x >= 0 && x < WW) {
        size_t off = (size_t)b * HWN + (size_t)y * WW + x;
        if (mask[off]) mkv = 1.f;
        vi = inp[off];
        vt = tgt[off];
      }
    }
    v_in[q] = vi; v_tg[q] = vt; mk[q] = mkv;
    k_in[q] = fkey(vi); k_tg[q] = fkey(vt);
  }

  // n = masked count
  float pn = 0.f;
  #pragma unroll
  for (int q = 0; q < 3; ++q) pn += mk[q];
  float nf = breduce256(pn, redf);
  int n = (int)(nf + 0.5f);
  int r = (n > 0) ? ((n - 1) >> 1) : 0;

  if (t == 0) {
    sh_pref[0] = 0; sh_pref[1] = 0;
    sh_rank[0] = r; sh_rank[1] = r;
  }
  __syncthreads();

  // 4 radix passes, 8 bits each, both signals per pass
  #pragma unroll
  for (int p = 0; p < 4; ++p) {
    const int shift = 24 - 8 * p;
    hist[t] = 0; hist[t + 256] = 0;
    __syncthreads();
    const int r_in = sh_rank[0], r_tg = sh_rank[1];
    const unsigned int pref_in = sh_pref[0], pref_tg = sh_pref[1];
    #pragma unroll
    for (int q = 0; q < 3; ++q) {
      if (mk[q] != 0.f) {
        unsigned int k = k_in[q];
        if (p == 0 || (k >> (shift + 8)) == pref_in)
          atomicAdd(&hist[(k >> shift) & 255u], 1u);
        unsigned int k2 = k_tg[q];
        if (p == 0 || (k2 >> (shift + 8)) == pref_tg)
          atomicAdd(&hist[256 + ((k2 >> shift) & 255u)], 1u);
      }
    }
    __syncthreads();
    // inclusive Hillis-Steele scan over both 256-bin halves
    scan[t] = hist[t]; scan[t + 256] = hist[t + 256];
    __syncthreads();
    #pragma unroll
    for (int d = 1; d < 256; d <<= 1) {
      unsigned int a = 0, b2 = 0;
      if (t >= d) { a = scan[t - d]; b2 = scan[256 + t - d]; }
      __syncthreads();
      scan[t] += a; scan[256 + t] += b2;
      __syncthreads();
    }
    // descend: find bin where cum_prev <= rank < cum
    unsigned int c1 = scan[t], p1 = (t > 0) ? scan[t - 1] : 0;
    if ((unsigned int)r_in >= p1 && (unsigned int)r_in < c1) {
      sh_pref[0] = (pref_in << 8) | (unsigned int)t;
      sh_rank[0] = r_in - (int)p1;
    }
    unsigned int c2 = scan[256 + t], p2 = (t > 0) ? scan[256 + t - 1] : 0;
    if ((unsigned int)r_tg >= p2 && (unsigned int)r_tg < c2) {
      sh_pref[1] = (pref_tg << 8) | (unsigned int)t;
      sh_rank[1] = r_tg - (int)p2;
    }
    __syncthreads();
  }

  float med_i = (n > 0) ? fkey_inv(sh_pref[0]) : 0.f;
  float med_t = (n > 0) ? fkey_inv(sh_pref[1]) : 0.f;

  // masked mean abs deviation (both signals in one reduce)
  float pi = 0.f, pt = 0.f;
  #pragma unroll
  for (int q = 0; q < 3; ++q) {
    if (mk[q] != 0.f) {
      pi += fabsf(v_in[q] - med_i);
      pt += fabsf(v_tg[q] - med_t);
    }
  }
  float2 ss = breduce256x2(pi, pt, redf);
  float si = fmaxf(ss.x / fmaxf(nf, 1.f), EPSV);
  float st = fmaxf(ss.y / fmaxf(nf, 1.f), EPSV);

  // masked mean of max(|norm_in - norm_tg|, EPS)
  float pe = 0.f;
  #pragma unroll
  for (int q = 0; q < 3; ++q) {
    if (mk[q] != 0.f) {
      float a = (v_in[q] - med_i) / si;
      float c = (v_tg[q] - med_t) / st;
      pe += fmaxf(fabsf(a - c), EPSV);
    }
  }
  float es = breduce256(pe, redf);
  if (t == 0) {
    ep[bk] = sqrtf(fmaxf(es / fmaxf(nf, 1.f), EPSV));
    val[bk] = (n >= 4) ? 1.f : 0.f;
  }
}

// ---------- K4: e_patch[b] ----------
__global__ __launch_bounds__(256) void preduce_kernel(const float* __restrict__ ep,
                                                      const float* __restrict__ val,
                                                      float* __restrict__ e_patch) {
  const int b = blockIdx.x;
  const int t = threadIdx.x;
  __shared__ float red[512];
  float se = 0.f, sv = 0.f;
  for (int i = t; i < KTOP; i += 256) {
    float v = val[b * KTOP + i];
    se += ep[b * KTOP + i] * v;
    sv += v;
  }
  float2 tt = breduce256x2(se, sv, red);
  if (t == 0) e_patch[b] = tt.x / fmaxf(tt.y, 1.f);
}

// ---------- K5a: wide histogram of top-14 key bits ----------
__global__ __launch_bounds__(256) void ghist_kernel(const float* __restrict__ inp,
                                                    const float* __restrict__ tgt,
                                                    const unsigned char* __restrict__ mask,
                                                    unsigned int* __restrict__ ghist) {
  const int bs = blockIdx.x / NSLICE;
  const int sl = blockIdx.x % NSLICE;
  const int b = bs >> 1, s = bs & 1;
  const float* x = (s == 0 ? inp : tgt) + (size_t)b * HWN;
  const unsigned char* m = mask + (size_t)b * HWN;
  __shared__ unsigned int hist[GBINS];
  const int t = threadIdx.x;
  for (int i = t; i < GBINS; i += 256) hist[i] = 0;
  __syncthreads();
  const int per = HWN / NSLICE;  // 19200
  const int i0 = sl * per;
  for (int i = i0 + t; i < i0 + per; i += 256) {
    if (m[i]) atomicAdd(&hist[fkey(x[i]) >> GSHIFT], 1u);
  }
  __syncthreads();
  unsigned int* gh = ghist + (size_t)bs * GBINS;
  for (int i = t; i < GBINS; i += 256) {
    unsigned int h = hist[i];
    if (h) atomicAdd(&gh[i], h);
  }
}

// ---------- K5b: find median bin, ranks, n_below ----------
__global__ __launch_bounds__(256) void gsel_kernel(const unsigned int* __restrict__ ghist,
                                                   int* __restrict__ sel) {
  const int bs = blockIdx.x;
  const int t = threadIdx.x;
  const unsigned int* gh = ghist + (size_t)bs * GBINS;
  __shared__ unsigned int part[256];
  unsigned int p = 0;
  const int per = GBINS / 256;  // 64
  for (int i = 0; i < per; ++i) p += gh[t * per + i];
  part[t] = p;
  __syncthreads();
  if (t == 0) {
    unsigned int n = 0;
    for (int i = 0; i < 256; ++i) n += part[i];
    int bstar = -1, r2 = 0;
    unsigned int nbelow = 0;
    if (n > 0) {
      unsigned int r = (n - 1) >> 1;
      unsigned int cum = 0;
      int seg = 0;
      for (; seg < 256; ++seg) {
        if (cum + part[seg] > r) break;
        cum += part[seg];
      }
      int bin = seg * per;
      for (;; ++bin) {
        unsigned int h = gh[bin];
        if (cum + h > r) break;
        cum += h;
      }
      bstar = bin;
      r2 = (int)(r - cum);
      nbelow = cum;
    }
    sel[bs * 4 + 0] = bstar;
    sel[bs * 4 + 1] = r2;
    sel[bs * 4 + 2] = (int)n;
    sel[bs * 4 + 3] = (int)nbelow;
  }
}

// ---------- K5c: collect candidates + below/above sums ----------
__global__ __launch_bounds__(256) void gcollect_kernel(const float* __restrict__ inp,
                                                       const float* __restrict__ tgt,
                                                       const unsigned char* __restrict__ mask,
                                                       const int* __restrict__ sel,
                                                       float* __restrict__ cand,
                                                       unsigned int* __restrict__ ccount,
                                                       float* __restrict__ sbelow,
                                                       float* __restrict__ sabove) {
  const int bs = blockIdx.x / NSLICE;
  const int sl = blockIdx.x % NSLICE;
  const int b = bs >> 1, s = bs & 1;
  const float* x = (s == 0 ? inp : tgt) + (size_t)b * HWN;
  const unsigned char* m = mask + (size_t)b * HWN;
  const int bstar = sel[bs * 4 + 0];
  __shared__ float red[512];
  const int t = threadIdx.x;
  const int per = HWN / NSLICE;
  const int i0 = sl * per;
  float sb = 0.f, sa = 0.f;
  if (bstar >= 0) {
    float* cd = cand + (size_t)bs * CAP;
    for (int i = i0 + t; i < i0 + per; i += 256) {
      if (m[i]) {
        float v = x[i];
        int bin = (int)(fkey(v) >> GSHIFT);
        if (bin < bstar) sb += v;
        else if (bin > bstar) sa += v;
        else {
          unsigned int pos = atomicAdd(&ccount[bs], 1u);
          if (pos < CAP) cd[pos] = v;
        }
      }
    }
  }
  float2 ts = breduce256x2(sb, sa, red);
  if (t == 0) {
    atomicAdd(&sbelow[bs], ts.x);
    atomicAdd(&sabove[bs], ts.y);
  }
}

// ---------- K5d: exact select among candidates + scale ----------
__global__ __launch_bounds__(256) void gfinal_kernel(const float* __restrict__ cand,
                                                     const unsigned int* __restrict__ ccount,
                                                     const int* __restrict__ sel,
                                                     const float* __restrict__ sbelow,
                                                     const float* __restrict__ sabove,
                                                     float* __restrict__ gstats,
                                                     float* __restrict__ nvals) {
  const int bs = blockIdx.x;
  const int t = threadIdx.x;
  const int bstar = sel[bs * 4 + 0];
  const int r2 = sel[bs * 4 + 1];
  const int n = sel[bs * 4 + 2];
  const int nbelow = sel[bs * 4 + 3];
  __shared__ unsigned int hist[512];
  __shared__ float red[256];
  __shared__ int sh_bin1, sh_r3;
  const float* cd = cand + (size_t)bs * CAP;
  int c = (int)min(ccount[bs], (unsigned int)CAP);
  if (bstar < 0) {
    if (t == 0) {
      gstats[bs * 2 + 0] = 0.f;
      gstats[bs * 2 + 1] = 0.f;
      if ((bs & 1) == 0) nvals[bs >> 1] = 0.f;
    }
    return;
  }

  // pass 1: bits [17:9]
  for (int i = t; i < 512; i += 256) hist[i] = 0;
  __syncthreads();
  for (int i = t; i < c; i += 256)
    atomicAdd(&hist[(fkey(cd[i]) >> 9) & 511u], 1u);
  __syncthreads();
  if (t == 0) {
    unsigned int rr = (unsigned int)r2, cum = 0;
    int bin = 0;
    for (; bin < 512; ++bin) {
      unsigned int h = hist[bin];
      if (cum + h > rr) break;
      cum += h;
    }
    sh_bin1 = bin;
    sh_r3 = (int)(rr - cum);
  }
  __syncthreads();
  const int bin1 = sh_bin1;
  const int r3 = sh_r3;

  // pass 2: bits [8:0]
  for (int i = t; i < 512; i += 256) hist[i] = 0;
  __syncthreads();
  for (int i = t; i < c; i += 256) {
    unsigned int key = fkey(cd[i]);
    if (((key >> 9) & 511u) == (unsigned int)bin1)
      atomicAdd(&hist[key & 511u], 1u);
  }
  __syncthreads();
  __shared__ float sh_med;
  if (t == 0) {
    unsigned int rr = (unsigned int)r3, cum = 0;
    int bin = 0;
    for (; bin < 512; ++bin) {
      unsigned int h = hist[bin];
      if (cum + h > rr) break;
      cum += h;
    }
    unsigned int key = ((unsigned int)bstar << GSHIFT) |
                       ((unsigned int)bin1 << 9) | (unsigned int)bin;
    sh_med = fkey_inv(key);
  }
  __syncthreads();
  const float med = sh_med;

  float ps = 0.f;
  for (int i = t; i < c; i += 256) ps += fabsf(cd[i] - med);
  float scand = breduce256(ps, red);
  if (t == 0) {
    float nb = (float)nbelow;
    float na = (float)(n - nbelow - c);
    float num = (nb * med - sbelow[bs]) + (sabove[bs] - na * med) + scand;
    gstats[bs * 2 + 0] = med;
    gstats[bs * 2 + 1] = num / fmaxf((float)n, 1.f);
    if ((bs & 1) == 0) nvals[bs >> 1] = (float)n;
  }
}

// ---------- K6a: global error partial sums ----------
__global__ __launch_bounds__(256) void gerr_kernel(const float* __restrict__ inp,
                                                   const float* __restrict__ tgt,
                                                   const unsigned char* __restrict__ mask,
                                                   const float* __restrict__ gstats,
                                                   float* __restrict__ gacc) {
  const int b = blockIdx.x / NSLICE;
  const int sl = blockIdx.x % NSLICE;
  const float* xi = inp + (size_t)b * HWN;
  const float* xt = tgt + (size_t)b * HWN;
  const unsigned char* m = mask + (size_t)b * HWN;
  __shared__ float red[256];
  const int t = threadIdx.x;
  const float med_i = gstats[(b * 2 + 0) * 2 + 0];
  const float sc_i = fmaxf(gstats[(b * 2 + 0) * 2 + 1], EPSV);
  const float med_t = gstats[(b * 2 + 1) * 2 + 0];
  const float sc_t = fmaxf(gstats[(b * 2 + 1) * 2 + 1], EPSV);
  const int per = HWN / NSLICE;
  const int i0 = sl * per;
  float part = 0.f;
  for (int i = i0 + t; i < i0 + per; i += 256) {
    if (m[i]) {
      float a = (xi[i] - med_i) / sc_i;
      float cc = (xt[i] - med_t) / sc_t;
      part += fmaxf(fabsf(a - cc), EPSV);
    }
  }
  float tp = breduce256(part, red);
  if (t == 0) atomicAdd(&gacc[b], tp);
}

// ---------- K6b: combine ----------
__global__ __launch_bounds__(64) void final_kernel(const float* __restrict__ gacc,
                                                   const float* __restrict__ nvals,
                                                   const float* __restrict__ e_patch,
                                                   float* __restrict__ out) {
  const int b = threadIdx.x;
  if (b < BB) {
    float n = nvals[b];
    float eg = sqrtf(fmaxf(gacc[b] / fmaxf(n, 1.f), EPSV));
    out[b] = 0.5f * (e_patch[b] + eg);
  }
}

extern "C" void kernel_launch(void* const* d_in, const int* in_sizes, int n_in,
                              void* d_out, int out_size, void* d_ws, size_t ws_size,
                              hipStream_t stream) {
  const float* inp = (const float*)d_in[0];
  const float* tgt = (const float*)d_in[1];
  const unsigned char* mask = (const unsigned char*)d_in[2];   // jax bool -> 1 byte
  const float* image = (const float*)d_in[3];
  const unsigned char* vmask = (const unsigned char*)d_in[4];  // jax bool -> 1 byte
  float* out = (float*)d_out;

  float* ws = (float*)d_ws;
  float* re = ws;                                   // 48960
  int* coords = (int*)(ws + 48960);                 // 9792
  float* ep = ws + 48960 + 9792;                    // 4896
  float* val = ep + 4896;                           // 4896
  float* e_patch = val + 4896;                      // 32
  float* gstats = e_patch + 32;                     // 128
  float* nvals = gstats + 128;                      // 32
  int* sel = (int*)(nvals + 32);                    // 256
  float* cand = (float*)(sel + 256);                // 64*CAP
  unsigned int* ghist = (unsigned int*)(cand + (size_t)64 * CAP);  // 64*GBINS
  unsigned int* ccount = ghist + (size_t)64 * GBINS;               // 64
  float* sbelow = (float*)(ccount + 64);                           // 64
  float* sabove = sbelow + 64;                                     // 64
  float* gacc = sabove + 64;                                       // 32
  size_t zero_bytes = ((size_t)64 * GBINS + 64 + 64 + 64 + 32) * 4;
  hipMemsetAsync(ghist, 0, zero_bytes, stream);

  edge_resize_kernel<<<(BB * OHW + 255) / 256, 256, 0, stream>>>(image, vmask, re);
  topk_kernel<<<BB, 256, 0, stream>>>(re, coords);
  patch_kernel<<<BB * KTOP, 256, 0, stream>>>(inp, tgt, mask, coords, ep, val);
  preduce_kernel<<<BB, 256, 0, stream>>>(ep, val, e_patch);
  ghist_kernel<<<BB * 2 * NSLICE, 256, 0, stream>>>(inp, tgt, mask, ghist);
  gsel_kernel<<<BB * 2, 256, 0, stream>>>(ghist, sel);
  gcollect_kernel<<<BB * 2 * NSLICE, 256, 0, stream>>>(inp, tgt, mask, sel, cand, ccount, sbelow, sabove);
  gfinal_kernel<<<BB * 2, 256, 0, stream>>>(cand, ccount, sel, sbelow, sabove, gstats, nvals);
  gerr_kernel<<<BB * NSLICE, 256, 0, stream>>>(inp, tgt, mask, gstats, gacc);
  final_kernel<<<1, 64, 0, stream>>>(gacc, nvals, e_patch, out);
}

// Round 4
// 782.404 us; speedup vs baseline: 2.9505x; 1.2458x over previous
//
#include <hip/hip_runtime.h>
#include <math.h>

// Problem constants (fixed by setup_inputs: B=32, H=480, W=640)
#define BB 32
#define HH 480
#define WW 640
#define HWN (HH * WW)
#define OH 34            // H // RESHAPE
#define OW 45            // W // RESHAPE
#define OHW (OH * OW)    // 1530
#define KTOP 153         // max(int(0.1*oh*ow), 10)
#define KS 25            // kernel size (odd)
#define PHW 12           // half kernel
#define PATCH (KS * KS)  // 625
#define RESHAPE_I 14
#define EPSV 1e-5f

// global-median machinery
#define GBINS 16384      // top-14 bits of monotone key
#define GSHIFT 18        // 32 - 14
#define NSLICE 16        // WGs per (b,s) for data passes
#define CAP 16384        // candidate cap per (b,s)
#define LCAP 4096        // per-WG LDS candidate buffer (expected ~220 used)
#define CPAD 32          // ccount stride in uints (128 B -> no false sharing)

// ---------- monotone float <-> uint key ----------
__device__ __forceinline__ unsigned int fkey(float f) {
  unsigned int u = __float_as_uint(f);
  return (u & 0x80000000u) ? ~u : (u | 0x80000000u);
}
__device__ __forceinline__ float fkey_inv(unsigned int k) {
  unsigned int u = (k & 0x80000000u) ? (k & 0x7FFFFFFFu) : ~k;
  return __uint_as_float(u);
}

// ---------- 256-thread block reduce (single) ----------
__device__ __forceinline__ float breduce256(float v, float* red) {
  const int t = threadIdx.x;
  __syncthreads();
  red[t] = v;
  __syncthreads();
  for (int s2 = 128; s2 > 0; s2 >>= 1) {
    if (t < s2) red[t] += red[t + s2];
    __syncthreads();
  }
  float r = red[0];
  __syncthreads();
  return r;
}

// ---------- 256-thread block reduce (pair) ----------
__device__ __forceinline__ float2 breduce256x2(float a, float b, float* red) {
  const int t = threadIdx.x;
  __syncthreads();
  red[t] = a;
  red[256 + t] = b;
  __syncthreads();
  for (int s2 = 128; s2 > 0; s2 >>= 1) {
    if (t < s2) {
      red[t] += red[t + s2];
      red[256 + t] += red[256 + t + s2];
    }
    __syncthreads();
  }
  float2 r = make_float2(red[0], red[256]);
  __syncthreads();
  return r;
}

// ---------- edge value at (b, y, x): sobel + erode(validity) + border mask ----------
__device__ float edge_at(const float* __restrict__ image, const unsigned char* __restrict__ vmask,
                         int b, int y, int x) {
  if (y < 3 || y >= HH - 3 || x < 3 || x >= WW - 3) return 0.f;
  const unsigned char* vm = vmask + (size_t)b * HWN;
  #pragma unroll
  for (int dy = -1; dy <= 1; ++dy) {
    #pragma unroll
    for (int dx = -1; dx <= 1; ++dx) {
      if (!vm[(size_t)(y + dy) * WW + (x + dx)]) return 0.f;
    }
  }
  const float* img = image + (size_t)b * 3 * HWN;
  float sx2 = 0.f, sy2 = 0.f;
  #pragma unroll
  for (int c = 0; c < 3; ++c) {
    const float* p = img + (size_t)c * HWN + (size_t)y * WW + x;
    float a00 = p[-WW - 1], a01 = p[-WW], a02 = p[-WW + 1];
    float a10 = p[-1],                    a12 = p[1];
    float a20 = p[WW - 1],  a21 = p[WW],  a22 = p[WW + 1];
    float gx = (-a00 + a02 + -2.f * a10 + 2.f * a12 + -a20 + a22) / 8.f;
    float gy = (-a00 + -2.f * a01 + -a02 + a20 + 2.f * a21 + a22) / 8.f;
    sx2 += gx * gx;
    sy2 += gy * gy;
  }
  float gxm = sqrtf(sx2 / 3.f);
  float gym = sqrtf(sy2 / 3.f);
  return sqrtf(gxm * gxm + gym * gym);
}

// ---------- K1: fused edge + bilinear resize ----------
__global__ __launch_bounds__(256) void edge_resize_kernel(const float* __restrict__ image,
                                                          const unsigned char* __restrict__ vmask,
                                                          float* __restrict__ re) {
  int id = blockIdx.x * 256 + threadIdx.x;
  if (id >= BB * OHW) return;
  int b = id / OHW;
  int rem = id % OHW;
  int oy = rem / OW, ox = rem % OW;

  const float ry = (float)((double)HH / (double)OH);
  const float rx = (float)((double)WW / (double)OW);
  float cy = fminf(fmaxf(((float)oy + 0.5f) * ry - 0.5f, 0.f), (float)(HH - 1));
  float cx = fminf(fmaxf(((float)ox + 0.5f) * rx - 0.5f, 0.f), (float)(WW - 1));
  int y0 = (int)floorf(cy);
  int x0 = (int)floorf(cx);
  int y1 = min(y0 + 1, HH - 1);
  int x1 = min(x0 + 1, WW - 1);
  float wy = cy - (float)y0;
  float wx = cx - (float)x0;

  float g00 = edge_at(image, vmask, b, y0, x0);
  float g01 = edge_at(image, vmask, b, y0, x1);
  float g10 = edge_at(image, vmask, b, y1, x0);
  float g11 = edge_at(image, vmask, b, y1, x1);
  re[id] = g00 * (1.f - wy) * (1.f - wx) + g01 * (1.f - wy) * wx +
           g10 * wy * (1.f - wx) + g11 * wy * wx;
}

// ---------- K2: exact stable top-k by rank counting ----------
__global__ __launch_bounds__(256) void topk_kernel(const float* __restrict__ re,
                                                   int* __restrict__ coords) {
  const int b = blockIdx.x;
  const int t = threadIdx.x;
  __shared__ float e[OHW];
  for (int i = t; i < OHW; i += 256) e[i] = re[b * OHW + i];
  __syncthreads();
  for (int i = t; i < OHW; i += 256) {
    float v = e[i];
    int rank = 0;
    for (int j = 0; j < OHW; ++j) {
      float u = e[j];
      rank += (u > v) || (u == v && j < i);
    }
    if (rank < KTOP) {
      coords[(b * KTOP + rank) * 2 + 0] = (i / OW) * RESHAPE_I;
      coords[(b * KTOP + rank) * 2 + 1] = (i % OW) * RESHAPE_I;
    }
  }
}

// ---------- K3: per-patch SSI error via exact LDS radix select ----------
__global__ __launch_bounds__(256) void patch_kernel(const float* __restrict__ inp,
                                                    const float* __restrict__ tgt,
                                                    const unsigned char* __restrict__ mask,
                                                    const int* __restrict__ coords,
                                                    float* __restrict__ ep, float* __restrict__ val) {
  const int bk = blockIdx.x;
  const int b = bk / KTOP;
  const int t = threadIdx.x;
  __shared__ unsigned int hist[512];   // [0:256) in, [256:512) tg
  __shared__ unsigned int scan[512];
  __shared__ float redf[512];
  __shared__ unsigned int sh_pref[2];
  __shared__ int sh_rank[2];

  const int cy = coords[bk * 2 + 0];
  const int cx = coords[bk * 2 + 1];

  float v_in[3], v_tg[3], mk[3];
  unsigned int k_in[3], k_tg[3];
  #pragma unroll
  for (int q = 0; q < 3; ++q) {
    int i = t + q * 256;
    float mkv = 0.f, vi = 0.f, vt = 0.f;
    if (i < PATCH) {
      int dy = i / KS - PHW, dx = i % KS - PHW;
      int y = cy + dy, x = cx + dx;
      if (y >= 0 && y < HH && x >= 0 && x < WW) {
        size_t off = (size_t)b * HWN + (size_t)y * WW + x;
        if (mask[off]) mkv = 1.f;
        vi = inp[off];
        vt = tgt[off];
      }
    }
    v_in[q] = vi; v_tg[q] = vt; mk[q] = mkv;
    k_in[q] = fkey(vi); k_tg[q] = fkey(vt);
  }

  float pn = 0.f;
  #pragma unroll
  for (int q = 0; q < 3; ++q) pn += mk[q];
  float nf = breduce256(pn, redf);
  int n = (int)(nf + 0.5f);
  int r = (n > 0) ? ((n - 1) >> 1) : 0;

  if (t == 0) {
    sh_pref[0] = 0; sh_pref[1] = 0;
    sh_rank[0] = r; sh_rank[1] = r;
  }
  __syncthreads();

  #pragma unroll
  for (int p = 0; p < 4; ++p) {
    const int shift = 24 - 8 * p;
    hist[t] = 0; hist[t + 256] = 0;
    __syncthreads();
    const int r_in = sh_rank[0], r_tg = sh_rank[1];
    const unsigned int pref_in = sh_pref[0], pref_tg = sh_pref[1];
    #pragma unroll
    for (int q = 0; q < 3; ++q) {
      if (mk[q] != 0.f) {
        unsigned int k = k_in[q];
        if (p == 0 || (k >> (shift + 8)) == pref_in)
          atomicAdd(&hist[(k >> shift) & 255u], 1u);
        unsigned int k2 = k_tg[q];
        if (p == 0 || (k2 >> (shift + 8)) == pref_tg)
          atomicAdd(&hist[256 + ((k2 >> shift) & 255u)], 1u);
      }
    }
    __syncthreads();
    scan[t] = hist[t]; scan[t + 256] = hist[t + 256];
    __syncthreads();
    #pragma unroll
    for (int d = 1; d < 256; d <<= 1) {
      unsigned int a = 0, b2 = 0;
      if (t >= d) { a = scan[t - d]; b2 = scan[256 + t - d]; }
      __syncthreads();
      scan[t] += a; scan[256 + t] += b2;
      __syncthreads();
    }
    unsigned int c1 = scan[t], p1 = (t > 0) ? scan[t - 1] : 0;
    if ((unsigned int)r_in >= p1 && (unsigned int)r_in < c1) {
      sh_pref[0] = (pref_in << 8) | (unsigned int)t;
      sh_rank[0] = r_in - (int)p1;
    }
    unsigned int c2 = scan[256 + t], p2 = (t > 0) ? scan[256 + t - 1] : 0;
    if ((unsigned int)r_tg >= p2 && (unsigned int)r_tg < c2) {
      sh_pref[1] = (pref_tg << 8) | (unsigned int)t;
      sh_rank[1] = r_tg - (int)p2;
    }
    __syncthreads();
  }

  float med_i = (n > 0) ? fkey_inv(sh_pref[0]) : 0.f;
  float med_t = (n > 0) ? fkey_inv(sh_pref[1]) : 0.f;

  float pi = 0.f, pt = 0.f;
  #pragma unroll
  for (int q = 0; q < 3; ++q) {
    if (mk[q] != 0.f) {
      pi += fabsf(v_in[q] - med_i);
      pt += fabsf(v_tg[q] - med_t);
    }
  }
  float2 ss = breduce256x2(pi, pt, redf);
  float si = fmaxf(ss.x / fmaxf(nf, 1.f), EPSV);
  float st = fmaxf(ss.y / fmaxf(nf, 1.f), EPSV);

  float pe = 0.f;
  #pragma unroll
  for (int q = 0; q < 3; ++q) {
    if (mk[q] != 0.f) {
      float a = (v_in[q] - med_i) / si;
      float c = (v_tg[q] - med_t) / st;
      pe += fmaxf(fabsf(a - c), EPSV);
    }
  }
  float es = breduce256(pe, redf);
  if (t == 0) {
    ep[bk] = sqrtf(fmaxf(es / fmaxf(nf, 1.f), EPSV));
    val[bk] = (n >= 4) ? 1.f : 0.f;
  }
}

// ---------- K4: e_patch[b] ----------
__global__ __launch_bounds__(256) void preduce_kernel(const float* __restrict__ ep,
                                                      const float* __restrict__ val,
                                                      float* __restrict__ e_patch) {
  const int b = blockIdx.x;
  const int t = threadIdx.x;
  __shared__ float red[512];
  float se = 0.f, sv = 0.f;
  for (int i = t; i < KTOP; i += 256) {
    float v = val[b * KTOP + i];
    se += ep[b * KTOP + i] * v;
    sv += v;
  }
  float2 tt = breduce256x2(se, sv, red);
  if (t == 0) e_patch[b] = tt.x / fmaxf(tt.y, 1.f);
}

// ---------- K5a: wide histogram of top-14 key bits ----------
__global__ __launch_bounds__(256) void ghist_kernel(const float* __restrict__ inp,
                                                    const float* __restrict__ tgt,
                                                    const unsigned char* __restrict__ mask,
                                                    unsigned int* __restrict__ ghist) {
  const int bs = blockIdx.x / NSLICE;
  const int sl = blockIdx.x % NSLICE;
  const int b = bs >> 1, s = bs & 1;
  const float* x = (s == 0 ? inp : tgt) + (size_t)b * HWN;
  const unsigned char* m = mask + (size_t)b * HWN;
  __shared__ unsigned int hist[GBINS];
  const int t = threadIdx.x;
  for (int i = t; i < GBINS; i += 256) hist[i] = 0;
  __syncthreads();
  const int per = HWN / NSLICE;  // 19200
  const int i0 = sl * per;
  for (int i = i0 + t; i < i0 + per; i += 256) {
    if (m[i]) atomicAdd(&hist[fkey(x[i]) >> GSHIFT], 1u);
  }
  __syncthreads();
  unsigned int* gh = ghist + (size_t)bs * GBINS;
  for (int i = t; i < GBINS; i += 256) {
    unsigned int h = hist[i];
    if (h) atomicAdd(&gh[i], h);
  }
}

// ---------- K5b: find median bin, ranks, n_below ----------
__global__ __launch_bounds__(256) void gsel_kernel(const unsigned int* __restrict__ ghist,
                                                   int* __restrict__ sel) {
  const int bs = blockIdx.x;
  const int t = threadIdx.x;
  const unsigned int* gh = ghist + (size_t)bs * GBINS;
  __shared__ unsigned int part[256];
  unsigned int p = 0;
  const int per = GBINS / 256;  // 64
  for (int i = 0; i < per; ++i) p += gh[t * per + i];
  part[t] = p;
  __syncthreads();
  if (t == 0) {
    unsigned int n = 0;
    for (int i = 0; i < 256; ++i) n += part[i];
    int bstar = -1, r2 = 0;
    unsigned int nbelow = 0;
    if (n > 0) {
      unsigned int r = (n - 1) >> 1;
      unsigned int cum = 0;
      int seg = 0;
      for (; seg < 256; ++seg) {
        if (cum + part[seg] > r) break;
        cum += part[seg];
      }
      int bin = seg * per;
      for (;; ++bin) {
        unsigned int h = gh[bin];
        if (cum + h > r) break;
        cum += h;
      }
      bstar = bin;
      r2 = (int)(r - cum);
      nbelow = cum;
    }
    sel[bs * 4 + 0] = bstar;
    sel[bs * 4 + 1] = r2;
    sel[bs * 4 + 2] = (int)n;
    sel[bs * 4 + 3] = (int)nbelow;
  }
}

// ---------- K5c: collect candidates + below/above sums ----------
// LDS-staged compaction: per-element LDS atomic, ONE global atomic per WG
// (padded counter), coalesced bulk flush. Overflow (>LCAP, ~18x headroom)
// falls back to per-element global reservation -- disjoint ranges, so the
// candidate SET is identical (order irrelevant to gfinal's histogram).
__global__ __launch_bounds__(256) void gcollect_kernel(const float* __restrict__ inp,
                                                       const float* __restrict__ tgt,
                                                       const unsigned char* __restrict__ mask,
                                                       const int* __restrict__ sel,
                                                       float* __restrict__ cand,
                                                       unsigned int* __restrict__ ccount,
                                                       float* __restrict__ sbelow,
                                                       float* __restrict__ sabove) {
  const int bs = blockIdx.x / NSLICE;
  const int sl = blockIdx.x % NSLICE;
  const int b = bs >> 1, s = bs & 1;
  const float* x = (s == 0 ? inp : tgt) + (size_t)b * HWN;
  const unsigned char* m = mask + (size_t)b * HWN;
  const int bstar = sel[bs * 4 + 0];
  __shared__ float red[512];
  __shared__ float buf[LCAP];
  __shared__ unsigned int lcnt, gbase;
  const int t = threadIdx.x;
  const int per = HWN / NSLICE;
  const int i0 = sl * per;
  if (t == 0) lcnt = 0;
  __syncthreads();
  float sb = 0.f, sa = 0.f;
  if (bstar >= 0) {
    float* cd = cand + (size_t)bs * CAP;
    for (int i = i0 + t; i < i0 + per; i += 256) {
      if (m[i]) {
        float v = x[i];
        int bin = (int)(fkey(v) >> GSHIFT);
        if (bin < bstar) sb += v;
        else if (bin > bstar) sa += v;
        else {
          unsigned int pos = atomicAdd(&lcnt, 1u);  // LDS atomic (intra-CU)
          if (pos < LCAP) {
            buf[pos] = v;
          } else {  // rare overflow path
            unsigned int g = atomicAdd(&ccount[bs * CPAD], 1u);
            if (g < CAP) cd[g] = v;
          }
        }
      }
    }
  }
  __syncthreads();
  if (bstar >= 0) {
    unsigned int c = min(lcnt, (unsigned int)LCAP);
    if (t == 0 && c > 0) gbase = atomicAdd(&ccount[bs * CPAD], c);
    __syncthreads();
    if (c > 0) {
      float* cd = cand + (size_t)bs * CAP;
      unsigned int base = gbase;
      for (unsigned int i = t; i < c; i += 256) {
        unsigned int pos = base + i;
        if (pos < CAP) cd[pos] = buf[i];
      }
    }
  }
  float2 ts = breduce256x2(sb, sa, red);
  if (t == 0) {
    atomicAdd(&sbelow[bs], ts.x);
    atomicAdd(&sabove[bs], ts.y);
  }
}

// ---------- K5d: exact select among candidates + scale ----------
__global__ __launch_bounds__(256) void gfinal_kernel(const float* __restrict__ cand,
                                                     const unsigned int* __restrict__ ccount,
                                                     const int* __restrict__ sel,
                                                     const float* __restrict__ sbelow,
                                                     const float* __restrict__ sabove,
                                                     float* __restrict__ gstats,
                                                     float* __restrict__ nvals) {
  const int bs = blockIdx.x;
  const int t = threadIdx.x;
  const int bstar = sel[bs * 4 + 0];
  const int r2 = sel[bs * 4 + 1];
  const int n = sel[bs * 4 + 2];
  const int nbelow = sel[bs * 4 + 3];
  __shared__ unsigned int hist[512];
  __shared__ float red[256];
  __shared__ int sh_bin1, sh_r3;
  const float* cd = cand + (size_t)bs * CAP;
  int c = (int)min(ccount[bs * CPAD], (unsigned int)CAP);
  if (bstar < 0) {
    if (t == 0) {
      gstats[bs * 2 + 0] = 0.f;
      gstats[bs * 2 + 1] = 0.f;
      if ((bs & 1) == 0) nvals[bs >> 1] = 0.f;
    }
    return;
  }

  // pass 1: bits [17:9]
  for (int i = t; i < 512; i += 256) hist[i] = 0;
  __syncthreads();
  for (int i = t; i < c; i += 256)
    atomicAdd(&hist[(fkey(cd[i]) >> 9) & 511u], 1u);
  __syncthreads();
  if (t == 0) {
    unsigned int rr = (unsigned int)r2, cum = 0;
    int bin = 0;
    for (; bin < 512; ++bin) {
      unsigned int h = hist[bin];
      if (cum + h > rr) break;
      cum += h;
    }
    sh_bin1 = bin;
    sh_r3 = (int)(rr - cum);
  }
  __syncthreads();
  const int bin1 = sh_bin1;
  const int r3 = sh_r3;

  // pass 2: bits [8:0]
  for (int i = t; i < 512; i += 256) hist[i] = 0;
  __syncthreads();
  for (int i = t; i < c; i += 256) {
    unsigned int key = fkey(cd[i]);
    if (((key >> 9) & 511u) == (unsigned int)bin1)
      atomicAdd(&hist[key & 511u], 1u);
  }
  __syncthreads();
  __shared__ float sh_med;
  if (t == 0) {
    unsigned int rr = (unsigned int)r3, cum = 0;
    int bin = 0;
    for (; bin < 512; ++bin) {
      unsigned int h = hist[bin];
      if (cum + h > rr) break;
      cum += h;
    }
    unsigned int key = ((unsigned int)bstar << GSHIFT) |
                       ((unsigned int)bin1 << 9) | (unsigned int)bin;
    sh_med = fkey_inv(key);
  }
  __syncthreads();
  const float med = sh_med;

  float ps = 0.f;
  for (int i = t; i < c; i += 256) ps += fabsf(cd[i] - med);
  float scand = breduce256(ps, red);
  if (t == 0) {
    float nb = (float)nbelow;
    float na = (float)(n - nbelow - c);
    float num = (nb * med - sbelow[bs]) + (sabove[bs] - na * med) + scand;
    gstats[bs * 2 + 0] = med;
    gstats[bs * 2 + 1] = num / fmaxf((float)n, 1.f);
    if ((bs & 1) == 0) nvals[bs >> 1] = (float)n;
  }
}

// ---------- K6a: global error partial sums ----------
__global__ __launch_bounds__(256) void gerr_kernel(const float* __restrict__ inp,
                                                   const float* __restrict__ tgt,
                                                   const unsigned char* __restrict__ mask,
                                                   const float* __restrict__ gstats,
                                                   float* __restrict__ gacc) {
  const int b = blockIdx.x / NSLICE;
  const int sl = blockIdx.x % NSLICE;
  const float* xi = inp + (size_t)b * HWN;
  const float* xt = tgt + (size_t)b * HWN;
  const unsigned char* m = mask + (size_t)b * HWN;
  __shared__ float red[256];
  const int t = threadIdx.x;
  const float med_i = gstats[(b * 2 + 0) * 2 + 0];
  const float sc_i = fmaxf(gstats[(b * 2 + 0) * 2 + 1], EPSV);
  const float med_t = gstats[(b * 2 + 1) * 2 + 0];
  const float sc_t = fmaxf(gstats[(b * 2 + 1) * 2 + 1], EPSV);
  const int per = HWN / NSLICE;
  const int i0 = sl * per;
  float part = 0.f;
  for (int i = i0 + t; i < i0 + per; i += 256) {
    if (m[i]) {
      float a = (xi[i] - med_i) / sc_i;
      float cc = (xt[i] - med_t) / sc_t;
      part += fmaxf(fabsf(a - cc), EPSV);
    }
  }
  float tp = breduce256(part, red);
  if (t == 0) atomicAdd(&gacc[b], tp);
}

// ---------- K6b: combine ----------
__global__ __launch_bounds__(64) void final_kernel(const float* __restrict__ gacc,
                                                   const float* __restrict__ nvals,
                                                   const float* __restrict__ e_patch,
                                                   float* __restrict__ out) {
  const int b = threadIdx.x;
  if (b < BB) {
    float n = nvals[b];
    float eg = sqrtf(fmaxf(gacc[b] / fmaxf(n, 1.f), EPSV));
    out[b] = 0.5f * (e_patch[b] + eg);
  }
}

extern "C" void kernel_launch(void* const* d_in, const int* in_sizes, int n_in,
                              void* d_out, int out_size, void* d_ws, size_t ws_size,
                              hipStream_t stream) {
  const float* inp = (const float*)d_in[0];
  const float* tgt = (const float*)d_in[1];
  const unsigned char* mask = (const unsigned char*)d_in[2];   // jax bool -> 1 byte
  const float* image = (const float*)d_in[3];
  const unsigned char* vmask = (const unsigned char*)d_in[4];  // jax bool -> 1 byte
  float* out = (float*)d_out;

  float* ws = (float*)d_ws;
  float* re = ws;                                   // 48960
  int* coords = (int*)(ws + 48960);                 // 9792
  float* ep = ws + 48960 + 9792;                    // 4896
  float* val = ep + 4896;                           // 4896
  float* e_patch = val + 4896;                      // 32
  float* gstats = e_patch + 32;                     // 128
  float* nvals = gstats + 128;                      // 32
  int* sel = (int*)(nvals + 32);                    // 256
  float* cand = (float*)(sel + 256);                // 64*CAP
  unsigned int* ghist = (unsigned int*)(cand + (size_t)64 * CAP);  // 64*GBINS
  unsigned int* ccount = ghist + (size_t)64 * GBINS;               // 64*CPAD
  float* sbelow = (float*)(ccount + 64 * CPAD);                    // 64
  float* sabove = sbelow + 64;                                     // 64
  float* gacc = sabove + 64;                                       // 32
  size_t zero_bytes = ((size_t)64 * GBINS + 64 * CPAD + 64 + 64 + 32) * 4;
  hipMemsetAsync(ghist, 0, zero_bytes, stream);

  edge_resize_kernel<<<(BB * OHW + 255) / 256, 256, 0, stream>>>(image, vmask, re);
  topk_kernel<<<BB, 256, 0, stream>>>(re, coords);
  patch_kernel<<<BB * KTOP, 256, 0, stream>>>(inp, tgt, mask, coords, ep, val);
  preduce_kernel<<<BB, 256, 0, stream>>>(ep, val, e_patch);
  ghist_kernel<<<BB * 2 * NSLICE, 256, 0, stream>>>(inp, tgt, mask, ghist);
  gsel_kernel<<<BB * 2, 256, 0, stream>>>(ghist, sel);
  gcollect_kernel<<<BB * 2 * NSLICE, 256, 0, stream>>>(inp, tgt, mask, sel, cand, ccount, sbelow, sabove);
  gfinal_kernel<<<BB * 2, 256, 0, stream>>>(cand, ccount, sel, sbelow, sabove, gstats, nvals);
  gerr_kernel<<<BB * NSLICE, 256, 0, stream>>>(inp, tgt, mask, gstats, gacc);
  final_kernel<<<1, 64, 0, stream>>>(gacc, nvals, e_patch, out);
}

// Round 5
// 615.861 us; speedup vs baseline: 3.7483x; 1.2704x over previous
//
#include <hip/hip_runtime.h>
#include <math.h>

// Problem constants (fixed by setup_inputs: B=32, H=480, W=640)
#define BB 32
#define HH 480
#define WW 640
#define HWN (HH * WW)
#define OH 34            // H // RESHAPE
#define OW 45            // W // RESHAPE
#define OHW (OH * OW)    // 1530
#define KTOP 153         // max(int(0.1*oh*ow), 10)
#define KS 25            // kernel size (odd)
#define PHW 12           // half kernel
#define PATCH (KS * KS)  // 625
#define RESHAPE_I 14
#define EPSV 1e-5f

// top-k machinery
#define TSLICE 10
#define TSW (OHW / TSLICE)   // 153 j's per slice

// global-median machinery
#define GBINS 16384      // top-14 bits of monotone key
#define GSHIFT 18        // 32 - 14
#define NSLICE 16        // WGs per (b,s) for data passes
#define CAP 16384        // candidate cap per (b,s)
#define LCAP 4096        // per-WG LDS candidate buffer (expected ~220 used)
#define CPAD 32          // ccount stride in uints (128 B -> no false sharing)

// ---------- monotone float <-> uint key ----------
__device__ __forceinline__ unsigned int fkey(float f) {
  unsigned int u = __float_as_uint(f);
  return (u & 0x80000000u) ? ~u : (u | 0x80000000u);
}
__device__ __forceinline__ float fkey_inv(unsigned int k) {
  unsigned int u = (k & 0x80000000u) ? (k & 0x7FFFFFFFu) : ~k;
  return __uint_as_float(u);
}

// ---------- 256-thread block reduce (single) ----------
__device__ __forceinline__ float breduce256(float v, float* red) {
  const int t = threadIdx.x;
  __syncthreads();
  red[t] = v;
  __syncthreads();
  for (int s2 = 128; s2 > 0; s2 >>= 1) {
    if (t < s2) red[t] += red[t + s2];
    __syncthreads();
  }
  float r = red[0];
  __syncthreads();
  return r;
}

// ---------- 256-thread block reduce (pair) ----------
__device__ __forceinline__ float2 breduce256x2(float a, float b, float* red) {
  const int t = threadIdx.x;
  __syncthreads();
  red[t] = a;
  red[256 + t] = b;
  __syncthreads();
  for (int s2 = 128; s2 > 0; s2 >>= 1) {
    if (t < s2) {
      red[t] += red[t + s2];
      red[256 + t] += red[256 + t + s2];
    }
    __syncthreads();
  }
  float2 r = make_float2(red[0], red[256]);
  __syncthreads();
  return r;
}

// ---------- edge value at (b, y, x): sobel + erode(validity) + border mask ----------
__device__ float edge_at(const float* __restrict__ image, const unsigned char* __restrict__ vmask,
                         int b, int y, int x) {
  if (y < 3 || y >= HH - 3 || x < 3 || x >= WW - 3) return 0.f;
  const unsigned char* vm = vmask + (size_t)b * HWN;
  #pragma unroll
  for (int dy = -1; dy <= 1; ++dy) {
    #pragma unroll
    for (int dx = -1; dx <= 1; ++dx) {
      if (!vm[(size_t)(y + dy) * WW + (x + dx)]) return 0.f;
    }
  }
  const float* img = image + (size_t)b * 3 * HWN;
  float sx2 = 0.f, sy2 = 0.f;
  #pragma unroll
  for (int c = 0; c < 3; ++c) {
    const float* p = img + (size_t)c * HWN + (size_t)y * WW + x;
    float a00 = p[-WW - 1], a01 = p[-WW], a02 = p[-WW + 1];
    float a10 = p[-1],                    a12 = p[1];
    float a20 = p[WW - 1],  a21 = p[WW],  a22 = p[WW + 1];
    float gx = (-a00 + a02 + -2.f * a10 + 2.f * a12 + -a20 + a22) / 8.f;
    float gy = (-a00 + -2.f * a01 + -a02 + a20 + 2.f * a21 + a22) / 8.f;
    sx2 += gx * gx;
    sy2 += gy * gy;
  }
  float gxm = sqrtf(sx2 / 3.f);
  float gym = sqrtf(sy2 / 3.f);
  return sqrtf(gxm * gxm + gym * gym);
}

// ---------- K1: fused edge + bilinear resize ----------
__global__ __launch_bounds__(256) void edge_resize_kernel(const float* __restrict__ image,
                                                          const unsigned char* __restrict__ vmask,
                                                          float* __restrict__ re) {
  int id = blockIdx.x * 256 + threadIdx.x;
  if (id >= BB * OHW) return;
  int b = id / OHW;
  int rem = id % OHW;
  int oy = rem / OW, ox = rem % OW;

  const float ry = (float)((double)HH / (double)OH);
  const float rx = (float)((double)WW / (double)OW);
  float cy = fminf(fmaxf(((float)oy + 0.5f) * ry - 0.5f, 0.f), (float)(HH - 1));
  float cx = fminf(fmaxf(((float)ox + 0.5f) * rx - 0.5f, 0.f), (float)(WW - 1));
  int y0 = (int)floorf(cy);
  int x0 = (int)floorf(cx);
  int y1 = min(y0 + 1, HH - 1);
  int x1 = min(x0 + 1, WW - 1);
  float wy = cy - (float)y0;
  float wx = cx - (float)x0;

  float g00 = edge_at(image, vmask, b, y0, x0);
  float g01 = edge_at(image, vmask, b, y0, x1);
  float g10 = edge_at(image, vmask, b, y1, x0);
  float g11 = edge_at(image, vmask, b, y1, x1);
  re[id] = g00 * (1.f - wy) * (1.f - wx) + g01 * (1.f - wy) * wx +
           g10 * wy * (1.f - wx) + g11 * wy * wx;
}

// ---------- K2a: partial ranks over j-slices ----------
// grid BB*TSLICE; WG loads all e to LDS, counts rank contributions of its
// 153-j slice for every i. j-outer / i-in-registers: 1 broadcast ds_read
// feeds 6 compares.
__global__ __launch_bounds__(256) void topk_rank_kernel(const float* __restrict__ re,
                                                        int* __restrict__ rpart) {
  const int b = blockIdx.x / TSLICE;
  const int sl = blockIdx.x % TSLICE;
  const int t = threadIdx.x;
  __shared__ float e[OHW];
  for (int i = t; i < OHW; i += 256) e[i] = re[b * OHW + i];
  __syncthreads();

  float vi[6];
  int idx[6], cnt[6];
  #pragma unroll
  for (int q = 0; q < 6; ++q) {
    int i = t + q * 256;
    idx[q] = i;
    vi[q] = (i < OHW) ? e[i] : 0.f;
    cnt[q] = 0;
  }
  const int j0 = sl * TSW;
  for (int jj = 0; jj < TSW; ++jj) {
    int j = j0 + jj;
    float u = e[j];  // broadcast
    #pragma unroll
    for (int q = 0; q < 6; ++q) {
      cnt[q] += (u > vi[q]) || (u == vi[q] && j < idx[q]);
    }
  }
  int* rp = rpart + ((size_t)b * TSLICE + sl) * OHW;
  #pragma unroll
  for (int q = 0; q < 6; ++q) {
    if (idx[q] < OHW) rp[idx[q]] = cnt[q];
  }
}

// ---------- K2b: sum partial ranks, scatter coords ----------
__global__ __launch_bounds__(256) void topk_write_kernel(const int* __restrict__ rpart,
                                                         int* __restrict__ coords) {
  const int b = blockIdx.x;
  const int t = threadIdx.x;
  const int* rp = rpart + (size_t)b * TSLICE * OHW;
  for (int i = t; i < OHW; i += 256) {
    int rank = 0;
    #pragma unroll
    for (int sl = 0; sl < TSLICE; ++sl) rank += rp[sl * OHW + i];
    if (rank < KTOP) {
      coords[(b * KTOP + rank) * 2 + 0] = (i / OW) * RESHAPE_I;
      coords[(b * KTOP + rank) * 2 + 1] = (i % OW) * RESHAPE_I;
    }
  }
}

// ---------- K3: per-patch SSI error via exact LDS radix select ----------
__global__ __launch_bounds__(256) void patch_kernel(const float* __restrict__ inp,
                                                    const float* __restrict__ tgt,
                                                    const unsigned char* __restrict__ mask,
                                                    const int* __restrict__ coords,
                                                    float* __restrict__ ep, float* __restrict__ val) {
  const int bk = blockIdx.x;
  const int b = bk / KTOP;
  const int t = threadIdx.x;
  __shared__ unsigned int hist[512];   // [0:256) in, [256:512) tg
  __shared__ unsigned int scan[512];
  __shared__ float redf[512];
  __shared__ unsigned int sh_pref[2];
  __shared__ int sh_rank[2];

  const int cy = coords[bk * 2 + 0];
  const int cx = coords[bk * 2 + 1];

  float v_in[3], v_tg[3], mk[3];
  unsigned int k_in[3], k_tg[3];
  #pragma unroll
  for (int q = 0; q < 3; ++q) {
    int i = t + q * 256;
    float mkv = 0.f, vi = 0.f, vt = 0.f;
    if (i < PATCH) {
      int dy = i / KS - PHW, dx = i % KS - PHW;
      int y = cy + dy, x = cx + dx;
      if (y >= 0 && y < HH && x >= 0 && x < WW) {
        size_t off = (size_t)b * HWN + (size_t)y * WW + x;
        if (mask[off]) mkv = 1.f;
        vi = inp[off];
        vt = tgt[off];
      }
    }
    v_in[q] = vi; v_tg[q] = vt; mk[q] = mkv;
    k_in[q] = fkey(vi); k_tg[q] = fkey(vt);
  }

  float pn = 0.f;
  #pragma unroll
  for (int q = 0; q < 3; ++q) pn += mk[q];
  float nf = breduce256(pn, redf);
  int n = (int)(nf + 0.5f);
  int r = (n > 0) ? ((n - 1) >> 1) : 0;

  if (t == 0) {
    sh_pref[0] = 0; sh_pref[1] = 0;
    sh_rank[0] = r; sh_rank[1] = r;
  }
  __syncthreads();

  #pragma unroll
  for (int p = 0; p < 4; ++p) {
    const int shift = 24 - 8 * p;
    hist[t] = 0; hist[t + 256] = 0;
    __syncthreads();
    const int r_in = sh_rank[0], r_tg = sh_rank[1];
    const unsigned int pref_in = sh_pref[0], pref_tg = sh_pref[1];
    #pragma unroll
    for (int q = 0; q < 3; ++q) {
      if (mk[q] != 0.f) {
        unsigned int k = k_in[q];
        if (p == 0 || (k >> (shift + 8)) == pref_in)
          atomicAdd(&hist[(k >> shift) & 255u], 1u);
        unsigned int k2 = k_tg[q];
        if (p == 0 || (k2 >> (shift + 8)) == pref_tg)
          atomicAdd(&hist[256 + ((k2 >> shift) & 255u)], 1u);
      }
    }
    __syncthreads();
    scan[t] = hist[t]; scan[t + 256] = hist[t + 256];
    __syncthreads();
    #pragma unroll
    for (int d = 1; d < 256; d <<= 1) {
      unsigned int a = 0, b2 = 0;
      if (t >= d) { a = scan[t - d]; b2 = scan[256 + t - d]; }
      __syncthreads();
      scan[t] += a; scan[256 + t] += b2;
      __syncthreads();
    }
    unsigned int c1 = scan[t], p1 = (t > 0) ? scan[t - 1] : 0;
    if ((unsigned int)r_in >= p1 && (unsigned int)r_in < c1) {
      sh_pref[0] = (pref_in << 8) | (unsigned int)t;
      sh_rank[0] = r_in - (int)p1;
    }
    unsigned int c2 = scan[256 + t], p2 = (t > 0) ? scan[256 + t - 1] : 0;
    if ((unsigned int)r_tg >= p2 && (unsigned int)r_tg < c2) {
      sh_pref[1] = (pref_tg << 8) | (unsigned int)t;
      sh_rank[1] = r_tg - (int)p2;
    }
    __syncthreads();
  }

  float med_i = (n > 0) ? fkey_inv(sh_pref[0]) : 0.f;
  float med_t = (n > 0) ? fkey_inv(sh_pref[1]) : 0.f;

  float pi = 0.f, pt = 0.f;
  #pragma unroll
  for (int q = 0; q < 3; ++q) {
    if (mk[q] != 0.f) {
      pi += fabsf(v_in[q] - med_i);
      pt += fabsf(v_tg[q] - med_t);
    }
  }
  float2 ss = breduce256x2(pi, pt, redf);
  float si = fmaxf(ss.x / fmaxf(nf, 1.f), EPSV);
  float st = fmaxf(ss.y / fmaxf(nf, 1.f), EPSV);

  float pe = 0.f;
  #pragma unroll
  for (int q = 0; q < 3; ++q) {
    if (mk[q] != 0.f) {
      float a = (v_in[q] - med_i) / si;
      float c = (v_tg[q] - med_t) / st;
      pe += fmaxf(fabsf(a - c), EPSV);
    }
  }
  float es = breduce256(pe, redf);
  if (t == 0) {
    ep[bk] = sqrtf(fmaxf(es / fmaxf(nf, 1.f), EPSV));
    val[bk] = (n >= 4) ? 1.f : 0.f;
  }
}

// ---------- K4: e_patch[b] ----------
__global__ __launch_bounds__(256) void preduce_kernel(const float* __restrict__ ep,
                                                      const float* __restrict__ val,
                                                      float* __restrict__ e_patch) {
  const int b = blockIdx.x;
  const int t = threadIdx.x;
  __shared__ float red[512];
  float se = 0.f, sv = 0.f;
  for (int i = t; i < KTOP; i += 256) {
    float v = val[b * KTOP + i];
    se += ep[b * KTOP + i] * v;
    sv += v;
  }
  float2 tt = breduce256x2(se, sv, red);
  if (t == 0) e_patch[b] = tt.x / fmaxf(tt.y, 1.f);
}

// ---------- K5a: wide histogram of top-14 key bits ----------
__global__ __launch_bounds__(256) void ghist_kernel(const float* __restrict__ inp,
                                                    const float* __restrict__ tgt,
                                                    const unsigned char* __restrict__ mask,
                                                    unsigned int* __restrict__ ghist) {
  const int bs = blockIdx.x / NSLICE;
  const int sl = blockIdx.x % NSLICE;
  const int b = bs >> 1, s = bs & 1;
  const float* x = (s == 0 ? inp : tgt) + (size_t)b * HWN;
  const unsigned char* m = mask + (size_t)b * HWN;
  __shared__ unsigned int hist[GBINS];
  const int t = threadIdx.x;
  for (int i = t; i < GBINS; i += 256) hist[i] = 0;
  __syncthreads();
  const int per = HWN / NSLICE;  // 19200
  const int i0 = sl * per;
  for (int i = i0 + t; i < i0 + per; i += 256) {
    if (m[i]) atomicAdd(&hist[fkey(x[i]) >> GSHIFT], 1u);
  }
  __syncthreads();
  unsigned int* gh = ghist + (size_t)bs * GBINS;
  for (int i = t; i < GBINS; i += 256) {
    unsigned int h = hist[i];
    if (h) atomicAdd(&gh[i], h);
  }
}

// ---------- K5b: find median bin, ranks, n_below ----------
__global__ __launch_bounds__(256) void gsel_kernel(const unsigned int* __restrict__ ghist,
                                                   int* __restrict__ sel) {
  const int bs = blockIdx.x;
  const int t = threadIdx.x;
  const unsigned int* gh = ghist + (size_t)bs * GBINS;
  __shared__ unsigned int part[256];
  unsigned int p = 0;
  const int per = GBINS / 256;  // 64
  for (int i = 0; i < per; ++i) p += gh[t * per + i];
  part[t] = p;
  __syncthreads();
  if (t == 0) {
    unsigned int n = 0;
    for (int i = 0; i < 256; ++i) n += part[i];
    int bstar = -1, r2 = 0;
    unsigned int nbelow = 0;
    if (n > 0) {
      unsigned int r = (n - 1) >> 1;
      unsigned int cum = 0;
      int seg = 0;
      for (; seg < 256; ++seg) {
        if (cum + part[seg] > r) break;
        cum += part[seg];
      }
      int bin = seg * per;
      for (;; ++bin) {
        unsigned int h = gh[bin];
        if (cum + h > r) break;
        cum += h;
      }
      bstar = bin;
      r2 = (int)(r - cum);
      nbelow = cum;
    }
    sel[bs * 4 + 0] = bstar;
    sel[bs * 4 + 1] = r2;
    sel[bs * 4 + 2] = (int)n;
    sel[bs * 4 + 3] = (int)nbelow;
  }
}

// ---------- K5c: collect candidates + below/above sums ----------
__global__ __launch_bounds__(256) void gcollect_kernel(const float* __restrict__ inp,
                                                       const float* __restrict__ tgt,
                                                       const unsigned char* __restrict__ mask,
                                                       const int* __restrict__ sel,
                                                       float* __restrict__ cand,
                                                       unsigned int* __restrict__ ccount,
                                                       float* __restrict__ sbelow,
                                                       float* __restrict__ sabove) {
  const int bs = blockIdx.x / NSLICE;
  const int sl = blockIdx.x % NSLICE;
  const int b = bs >> 1, s = bs & 1;
  const float* x = (s == 0 ? inp : tgt) + (size_t)b * HWN;
  const unsigned char* m = mask + (size_t)b * HWN;
  const int bstar = sel[bs * 4 + 0];
  __shared__ float red[512];
  __shared__ float buf[LCAP];
  __shared__ unsigned int lcnt, gbase;
  const int t = threadIdx.x;
  const int per = HWN / NSLICE;
  const int i0 = sl * per;
  if (t == 0) lcnt = 0;
  __syncthreads();
  float sb = 0.f, sa = 0.f;
  if (bstar >= 0) {
    float* cd = cand + (size_t)bs * CAP;
    for (int i = i0 + t; i < i0 + per; i += 256) {
      if (m[i]) {
        float v = x[i];
        int bin = (int)(fkey(v) >> GSHIFT);
        if (bin < bstar) sb += v;
        else if (bin > bstar) sa += v;
        else {
          unsigned int pos = atomicAdd(&lcnt, 1u);  // LDS atomic (intra-CU)
          if (pos < LCAP) {
            buf[pos] = v;
          } else {  // rare overflow path
            unsigned int g = atomicAdd(&ccount[bs * CPAD], 1u);
            if (g < CAP) cd[g] = v;
          }
        }
      }
    }
  }
  __syncthreads();
  if (bstar >= 0) {
    unsigned int c = min(lcnt, (unsigned int)LCAP);
    if (t == 0 && c > 0) gbase = atomicAdd(&ccount[bs * CPAD], c);
    __syncthreads();
    if (c > 0) {
      float* cd = cand + (size_t)bs * CAP;
      unsigned int base = gbase;
      for (unsigned int i = t; i < c; i += 256) {
        unsigned int pos = base + i;
        if (pos < CAP) cd[pos] = buf[i];
      }
    }
  }
  float2 ts = breduce256x2(sb, sa, red);
  if (t == 0) {
    atomicAdd(&sbelow[bs], ts.x);
    atomicAdd(&sabove[bs], ts.y);
  }
}

// ---------- K5d: exact select among candidates + scale ----------
__global__ __launch_bounds__(256) void gfinal_kernel(const float* __restrict__ cand,
                                                     const unsigned int* __restrict__ ccount,
                                                     const int* __restrict__ sel,
                                                     const float* __restrict__ sbelow,
                                                     const float* __restrict__ sabove,
                                                     float* __restrict__ gstats,
                                                     float* __restrict__ nvals) {
  const int bs = blockIdx.x;
  const int t = threadIdx.x;
  const int bstar = sel[bs * 4 + 0];
  const int r2 = sel[bs * 4 + 1];
  const int n = sel[bs * 4 + 2];
  const int nbelow = sel[bs * 4 + 3];
  __shared__ unsigned int hist[512];
  __shared__ float red[256];
  __shared__ int sh_bin1, sh_r3;
  const float* cd = cand + (size_t)bs * CAP;
  int c = (int)min(ccount[bs * CPAD], (unsigned int)CAP);
  if (bstar < 0) {
    if (t == 0) {
      gstats[bs * 2 + 0] = 0.f;
      gstats[bs * 2 + 1] = 0.f;
      if ((bs & 1) == 0) nvals[bs >> 1] = 0.f;
    }
    return;
  }

  // pass 1: bits [17:9]
  for (int i = t; i < 512; i += 256) hist[i] = 0;
  __syncthreads();
  for (int i = t; i < c; i += 256)
    atomicAdd(&hist[(fkey(cd[i]) >> 9) & 511u], 1u);
  __syncthreads();
  if (t == 0) {
    unsigned int rr = (unsigned int)r2, cum = 0;
    int bin = 0;
    for (; bin < 512; ++bin) {
      unsigned int h = hist[bin];
      if (cum + h > rr) break;
      cum += h;
    }
    sh_bin1 = bin;
    sh_r3 = (int)(rr - cum);
  }
  __syncthreads();
  const int bin1 = sh_bin1;
  const int r3 = sh_r3;

  // pass 2: bits [8:0]
  for (int i = t; i < 512; i += 256) hist[i] = 0;
  __syncthreads();
  for (int i = t; i < c; i += 256) {
    unsigned int key = fkey(cd[i]);
    if (((key >> 9) & 511u) == (unsigned int)bin1)
      atomicAdd(&hist[key & 511u], 1u);
  }
  __syncthreads();
  __shared__ float sh_med;
  if (t == 0) {
    unsigned int rr = (unsigned int)r3, cum = 0;
    int bin = 0;
    for (; bin < 512; ++bin) {
      unsigned int h = hist[bin];
      if (cum + h > rr) break;
      cum += h;
    }
    unsigned int key = ((unsigned int)bstar << GSHIFT) |
                       ((unsigned int)bin1 << 9) | (unsigned int)bin;
    sh_med = fkey_inv(key);
  }
  __syncthreads();
  const float med = sh_med;

  float ps = 0.f;
  for (int i = t; i < c; i += 256) ps += fabsf(cd[i] - med);
  float scand = breduce256(ps, red);
  if (t == 0) {
    float nb = (float)nbelow;
    float na = (float)(n - nbelow - c);
    float num = (nb * med - sbelow[bs]) + (sabove[bs] - na * med) + scand;
    gstats[bs * 2 + 0] = med;
    gstats[bs * 2 + 1] = num / fmaxf((float)n, 1.f);
    if ((bs & 1) == 0) nvals[bs >> 1] = (float)n;
  }
}

// ---------- K6a: global error partial sums ----------
__global__ __launch_bounds__(256) void gerr_kernel(const float* __restrict__ inp,
                                                   const float* __restrict__ tgt,
                                                   const unsigned char* __restrict__ mask,
                                                   const float* __restrict__ gstats,
                                                   float* __restrict__ gacc) {
  const int b = blockIdx.x / NSLICE;
  const int sl = blockIdx.x % NSLICE;
  const float* xi = inp + (size_t)b * HWN;
  const float* xt = tgt + (size_t)b * HWN;
  const unsigned char* m = mask + (size_t)b * HWN;
  __shared__ float red[256];
  const int t = threadIdx.x;
  const float med_i = gstats[(b * 2 + 0) * 2 + 0];
  const float sc_i = fmaxf(gstats[(b * 2 + 0) * 2 + 1], EPSV);
  const float med_t = gstats[(b * 2 + 1) * 2 + 0];
  const float sc_t = fmaxf(gstats[(b * 2 + 1) * 2 + 1], EPSV);
  const int per = HWN / NSLICE;
  const int i0 = sl * per;
  float part = 0.f;
  for (int i = i0 + t; i < i0 + per; i += 256) {
    if (m[i]) {
      float a = (xi[i] - med_i) / sc_i;
      float cc = (xt[i] - med_t) / sc_t;
      part += fmaxf(fabsf(a - cc), EPSV);
    }
  }
  float tp = breduce256(part, red);
  if (t == 0) atomicAdd(&gacc[b], tp);
}

// ---------- K6b: combine ----------
__global__ __launch_bounds__(64) void final_kernel(const float* __restrict__ gacc,
                                                   const float* __restrict__ nvals,
                                                   const float* __restrict__ e_patch,
                                                   float* __restrict__ out) {
  const int b = threadIdx.x;
  if (b < BB) {
    float n = nvals[b];
    float eg = sqrtf(fmaxf(gacc[b] / fmaxf(n, 1.f), EPSV));
    out[b] = 0.5f * (e_patch[b] + eg);
  }
}

extern "C" void kernel_launch(void* const* d_in, const int* in_sizes, int n_in,
                              void* d_out, int out_size, void* d_ws, size_t ws_size,
                              hipStream_t stream) {
  const float* inp = (const float*)d_in[0];
  const float* tgt = (const float*)d_in[1];
  const unsigned char* mask = (const unsigned char*)d_in[2];   // jax bool -> 1 byte
  const float* image = (const float*)d_in[3];
  const unsigned char* vmask = (const unsigned char*)d_in[4];  // jax bool -> 1 byte
  float* out = (float*)d_out;

  float* ws = (float*)d_ws;
  float* re = ws;                                   // 48960
  int* coords = (int*)(ws + 48960);                 // 9792
  float* ep = ws + 48960 + 9792;                    // 4896
  float* val = ep + 4896;                           // 4896
  float* e_patch = val + 4896;                      // 32
  float* gstats = e_patch + 32;                     // 128
  float* nvals = gstats + 128;                      // 32
  int* sel = (int*)(nvals + 32);                    // 256
  float* cand = (float*)(sel + 256);                // 64*CAP
  unsigned int* ghist = (unsigned int*)(cand + (size_t)64 * CAP);  // 64*GBINS
  unsigned int* ccount = ghist + (size_t)64 * GBINS;               // 64*CPAD
  float* sbelow = (float*)(ccount + 64 * CPAD);                    // 64
  float* sabove = sbelow + 64;                                     // 64
  float* gacc = sabove + 64;                                       // 32
  size_t zero_bytes = ((size_t)64 * GBINS + 64 * CPAD + 64 + 64 + 32) * 4;
  hipMemsetAsync(ghist, 0, zero_bytes, stream);

  // rpart (BB*TSLICE*OHW = 489,600 ints) aliases cand: topk finishes before
  // gcollect writes cand (stream-ordered), and coords is consumed by patch.
  int* rpart = (int*)cand;

  edge_resize_kernel<<<(BB * OHW + 255) / 256, 256, 0, stream>>>(image, vmask, re);
  topk_rank_kernel<<<BB * TSLICE, 256, 0, stream>>>(re, rpart);
  topk_write_kernel<<<BB, 256, 0, stream>>>(rpart, coords);
  patch_kernel<<<BB * KTOP, 256, 0, stream>>>(inp, tgt, mask, coords, ep, val);
  preduce_kernel<<<BB, 256, 0, stream>>>(ep, val, e_patch);
  ghist_kernel<<<BB * 2 * NSLICE, 256, 0, stream>>>(inp, tgt, mask, ghist);
  gsel_kernel<<<BB * 2, 256, 0, stream>>>(ghist, sel);
  gcollect_kernel<<<BB * 2 * NSLICE, 256, 0, stream>>>(inp, tgt, mask, sel, cand, ccount, sbelow, sabove);
  gfinal_kernel<<<BB * 2, 256, 0, stream>>>(cand, ccount, sel, sbelow, sabove, gstats, nvals);
  gerr_kernel<<<BB * NSLICE, 256, 0, stream>>>(inp, tgt, mask, gstats, gacc);
  final_kernel<<<1, 64, 0, stream>>>(gacc, nvals, e_patch, out);
}

// Round 6
// 451.408 us; speedup vs baseline: 5.1139x; 1.3643x over previous
//
#include <hip/hip_runtime.h>
#include <math.h>

// Problem constants (fixed by setup_inputs: B=32, H=480, W=640)
#define BB 32
#define HH 480
#define WW 640
#define HWN (HH * WW)
#define OH 34            // H // RESHAPE
#define OW 45            // W // RESHAPE
#define OHW (OH * OW)    // 1530
#define KTOP 153         // max(int(0.1*oh*ow), 10)
#define KS 25            // kernel size (odd)
#define PHW 12           // half kernel
#define PATCH (KS * KS)  // 625
#define RESHAPE_I 14
#define EPSV 1e-5f

// top-k machinery
#define TSLICE 10
#define TSW (OHW / TSLICE)   // 153 j's per slice

// global-median machinery: two 8-bit radix levels (256 bins each)
#define NSLICE 16        // WGs per batch for data passes
#define CAP 16384        // candidate cap per (b,s)
#define LCAP 2048        // per-WG LDS candidate buffer (expected ~40 used)
#define CPAD 32          // ccount stride in uints (128 B -> no false sharing)

// ---------- monotone float <-> uint key ----------
__device__ __forceinline__ unsigned int fkey(float f) {
  unsigned int u = __float_as_uint(f);
  return (u & 0x80000000u) ? ~u : (u | 0x80000000u);
}
__device__ __forceinline__ float fkey_inv(unsigned int k) {
  unsigned int u = (k & 0x80000000u) ? (k & 0x7FFFFFFFu) : ~k;
  return __uint_as_float(u);
}

// ---------- 256-thread block reduce (single) ----------
__device__ __forceinline__ float breduce256(float v, float* red) {
  const int t = threadIdx.x;
  __syncthreads();
  red[t] = v;
  __syncthreads();
  for (int s2 = 128; s2 > 0; s2 >>= 1) {
    if (t < s2) red[t] += red[t + s2];
    __syncthreads();
  }
  float r = red[0];
  __syncthreads();
  return r;
}

// ---------- 256-thread block reduce (pair) ----------
__device__ __forceinline__ float2 breduce256x2(float a, float b, float* red) {
  const int t = threadIdx.x;
  __syncthreads();
  red[t] = a;
  red[256 + t] = b;
  __syncthreads();
  for (int s2 = 128; s2 > 0; s2 >>= 1) {
    if (t < s2) {
      red[t] += red[t + s2];
      red[256 + t] += red[256 + t + s2];
    }
    __syncthreads();
  }
  float2 r = make_float2(red[0], red[256]);
  __syncthreads();
  return r;
}

// ---------- edge value at (b, y, x): sobel + erode(validity) + border mask ----------
__device__ float edge_at(const float* __restrict__ image, const unsigned char* __restrict__ vmask,
                         int b, int y, int x) {
  if (y < 3 || y >= HH - 3 || x < 3 || x >= WW - 3) return 0.f;
  const unsigned char* vm = vmask + (size_t)b * HWN;
  #pragma unroll
  for (int dy = -1; dy <= 1; ++dy) {
    #pragma unroll
    for (int dx = -1; dx <= 1; ++dx) {
      if (!vm[(size_t)(y + dy) * WW + (x + dx)]) return 0.f;
    }
  }
  const float* img = image + (size_t)b * 3 * HWN;
  float sx2 = 0.f, sy2 = 0.f;
  #pragma unroll
  for (int c = 0; c < 3; ++c) {
    const float* p = img + (size_t)c * HWN + (size_t)y * WW + x;
    float a00 = p[-WW - 1], a01 = p[-WW], a02 = p[-WW + 1];
    float a10 = p[-1],                    a12 = p[1];
    float a20 = p[WW - 1],  a21 = p[WW],  a22 = p[WW + 1];
    float gx = (-a00 + a02 + -2.f * a10 + 2.f * a12 + -a20 + a22) / 8.f;
    float gy = (-a00 + -2.f * a01 + -a02 + a20 + 2.f * a21 + a22) / 8.f;
    sx2 += gx * gx;
    sy2 += gy * gy;
  }
  float gxm = sqrtf(sx2 / 3.f);
  float gym = sqrtf(sy2 / 3.f);
  return sqrtf(gxm * gxm + gym * gym);
}

// ---------- K1: fused edge + bilinear resize ----------
__global__ __launch_bounds__(256) void edge_resize_kernel(const float* __restrict__ image,
                                                          const unsigned char* __restrict__ vmask,
                                                          float* __restrict__ re) {
  int id = blockIdx.x * 256 + threadIdx.x;
  if (id >= BB * OHW) return;
  int b = id / OHW;
  int rem = id % OHW;
  int oy = rem / OW, ox = rem % OW;

  const float ry = (float)((double)HH / (double)OH);
  const float rx = (float)((double)WW / (double)OW);
  float cy = fminf(fmaxf(((float)oy + 0.5f) * ry - 0.5f, 0.f), (float)(HH - 1));
  float cx = fminf(fmaxf(((float)ox + 0.5f) * rx - 0.5f, 0.f), (float)(WW - 1));
  int y0 = (int)floorf(cy);
  int x0 = (int)floorf(cx);
  int y1 = min(y0 + 1, HH - 1);
  int x1 = min(x0 + 1, WW - 1);
  float wy = cy - (float)y0;
  float wx = cx - (float)x0;

  float g00 = edge_at(image, vmask, b, y0, x0);
  float g01 = edge_at(image, vmask, b, y0, x1);
  float g10 = edge_at(image, vmask, b, y1, x0);
  float g11 = edge_at(image, vmask, b, y1, x1);
  re[id] = g00 * (1.f - wy) * (1.f - wx) + g01 * (1.f - wy) * wx +
           g10 * wy * (1.f - wx) + g11 * wy * wx;
}

// ---------- K2a: partial ranks over j-slices ----------
__global__ __launch_bounds__(256) void topk_rank_kernel(const float* __restrict__ re,
                                                        int* __restrict__ rpart) {
  const int b = blockIdx.x / TSLICE;
  const int sl = blockIdx.x % TSLICE;
  const int t = threadIdx.x;
  __shared__ float e[OHW];
  for (int i = t; i < OHW; i += 256) e[i] = re[b * OHW + i];
  __syncthreads();

  float vi[6];
  int idx[6], cnt[6];
  #pragma unroll
  for (int q = 0; q < 6; ++q) {
    int i = t + q * 256;
    idx[q] = i;
    vi[q] = (i < OHW) ? e[i] : 0.f;
    cnt[q] = 0;
  }
  const int j0 = sl * TSW;
  for (int jj = 0; jj < TSW; ++jj) {
    int j = j0 + jj;
    float u = e[j];  // broadcast
    #pragma unroll
    for (int q = 0; q < 6; ++q) {
      cnt[q] += (u > vi[q]) || (u == vi[q] && j < idx[q]);
    }
  }
  int* rp = rpart + ((size_t)b * TSLICE + sl) * OHW;
  #pragma unroll
  for (int q = 0; q < 6; ++q) {
    if (idx[q] < OHW) rp[idx[q]] = cnt[q];
  }
}

// ---------- K2b: sum partial ranks, scatter coords ----------
__global__ __launch_bounds__(256) void topk_write_kernel(const int* __restrict__ rpart,
                                                         int* __restrict__ coords) {
  const int b = blockIdx.x;
  const int t = threadIdx.x;
  const int* rp = rpart + (size_t)b * TSLICE * OHW;
  for (int i = t; i < OHW; i += 256) {
    int rank = 0;
    #pragma unroll
    for (int sl = 0; sl < TSLICE; ++sl) rank += rp[sl * OHW + i];
    if (rank < KTOP) {
      coords[(b * KTOP + rank) * 2 + 0] = (i / OW) * RESHAPE_I;
      coords[(b * KTOP + rank) * 2 + 1] = (i % OW) * RESHAPE_I;
    }
  }
}

// ---------- K3: per-patch SSI error via exact LDS radix select ----------
__global__ __launch_bounds__(256) void patch_kernel(const float* __restrict__ inp,
                                                    const float* __restrict__ tgt,
                                                    const unsigned char* __restrict__ mask,
                                                    const int* __restrict__ coords,
                                                    float* __restrict__ ep, float* __restrict__ val) {
  const int bk = blockIdx.x;
  const int b = bk / KTOP;
  const int t = threadIdx.x;
  __shared__ unsigned int hist[512];   // [0:256) in, [256:512) tg
  __shared__ unsigned int scan[512];
  __shared__ float redf[512];
  __shared__ unsigned int sh_pref[2];
  __shared__ int sh_rank[2];

  const int cy = coords[bk * 2 + 0];
  const int cx = coords[bk * 2 + 1];

  float v_in[3], v_tg[3], mk[3];
  unsigned int k_in[3], k_tg[3];
  #pragma unroll
  for (int q = 0; q < 3; ++q) {
    int i = t + q * 256;
    float mkv = 0.f, vi = 0.f, vt = 0.f;
    if (i < PATCH) {
      int dy = i / KS - PHW, dx = i % KS - PHW;
      int y = cy + dy, x = cx + dx;
      if (y >= 0 && y < HH && x >= 0 && x < WW) {
        size_t off = (size_t)b * HWN + (size_t)y * WW + x;
        if (mask[off]) mkv = 1.f;
        vi = inp[off];
        vt = tgt[off];
      }
    }
    v_in[q] = vi; v_tg[q] = vt; mk[q] = mkv;
    k_in[q] = fkey(vi); k_tg[q] = fkey(vt);
  }

  float pn = 0.f;
  #pragma unroll
  for (int q = 0; q < 3; ++q) pn += mk[q];
  float nf = breduce256(pn, redf);
  int n = (int)(nf + 0.5f);
  int r = (n > 0) ? ((n - 1) >> 1) : 0;

  if (t == 0) {
    sh_pref[0] = 0; sh_pref[1] = 0;
    sh_rank[0] = r; sh_rank[1] = r;
  }
  __syncthreads();

  #pragma unroll
  for (int p = 0; p < 4; ++p) {
    const int shift = 24 - 8 * p;
    hist[t] = 0; hist[t + 256] = 0;
    __syncthreads();
    const int r_in = sh_rank[0], r_tg = sh_rank[1];
    const unsigned int pref_in = sh_pref[0], pref_tg = sh_pref[1];
    #pragma unroll
    for (int q = 0; q < 3; ++q) {
      if (mk[q] != 0.f) {
        unsigned int k = k_in[q];
        if (p == 0 || (k >> (shift + 8)) == pref_in)
          atomicAdd(&hist[(k >> shift) & 255u], 1u);
        unsigned int k2 = k_tg[q];
        if (p == 0 || (k2 >> (shift + 8)) == pref_tg)
          atomicAdd(&hist[256 + ((k2 >> shift) & 255u)], 1u);
      }
    }
    __syncthreads();
    scan[t] = hist[t]; scan[t + 256] = hist[t + 256];
    __syncthreads();
    #pragma unroll
    for (int d = 1; d < 256; d <<= 1) {
      unsigned int a = 0, b2 = 0;
      if (t >= d) { a = scan[t - d]; b2 = scan[256 + t - d]; }
      __syncthreads();
      scan[t] += a; scan[256 + t] += b2;
      __syncthreads();
    }
    unsigned int c1 = scan[t], p1 = (t > 0) ? scan[t - 1] : 0;
    if ((unsigned int)r_in >= p1 && (unsigned int)r_in < c1) {
      sh_pref[0] = (pref_in << 8) | (unsigned int)t;
      sh_rank[0] = r_in - (int)p1;
    }
    unsigned int c2 = scan[256 + t], p2 = (t > 0) ? scan[256 + t - 1] : 0;
    if ((unsigned int)r_tg >= p2 && (unsigned int)r_tg < c2) {
      sh_pref[1] = (pref_tg << 8) | (unsigned int)t;
      sh_rank[1] = r_tg - (int)p2;
    }
    __syncthreads();
  }

  float med_i = (n > 0) ? fkey_inv(sh_pref[0]) : 0.f;
  float med_t = (n > 0) ? fkey_inv(sh_pref[1]) : 0.f;

  float pi = 0.f, pt = 0.f;
  #pragma unroll
  for (int q = 0; q < 3; ++q) {
    if (mk[q] != 0.f) {
      pi += fabsf(v_in[q] - med_i);
      pt += fabsf(v_tg[q] - med_t);
    }
  }
  float2 ss = breduce256x2(pi, pt, redf);
  float si = fmaxf(ss.x / fmaxf(nf, 1.f), EPSV);
  float st = fmaxf(ss.y / fmaxf(nf, 1.f), EPSV);

  float pe = 0.f;
  #pragma unroll
  for (int q = 0; q < 3; ++q) {
    if (mk[q] != 0.f) {
      float a = (v_in[q] - med_i) / si;
      float c = (v_tg[q] - med_t) / st;
      pe += fmaxf(fabsf(a - c), EPSV);
    }
  }
  float es = breduce256(pe, redf);
  if (t == 0) {
    ep[bk] = sqrtf(fmaxf(es / fmaxf(nf, 1.f), EPSV));
    val[bk] = (n >= 4) ? 1.f : 0.f;
  }
}

// ---------- K4: e_patch[b] ----------
__global__ __launch_bounds__(256) void preduce_kernel(const float* __restrict__ ep,
                                                      const float* __restrict__ val,
                                                      float* __restrict__ e_patch) {
  const int b = blockIdx.x;
  const int t = threadIdx.x;
  __shared__ float red[512];
  float se = 0.f, sv = 0.f;
  for (int i = t; i < KTOP; i += 256) {
    float v = val[b * KTOP + i];
    se += ep[b * KTOP + i] * v;
    sv += v;
  }
  float2 tt = breduce256x2(se, sv, red);
  if (t == 0) e_patch[b] = tt.x / fmaxf(tt.y, 1.f);
}

// ---------- K5a: level-1 digit histogram (key>>24), both signals ----------
// grid BB*NSLICE; 512-bin LDS (2 KiB) -> full occupancy; float4/uint vector loads.
__global__ __launch_bounds__(256) void gpassA_kernel(const float* __restrict__ inp,
                                                     const float* __restrict__ tgt,
                                                     const unsigned char* __restrict__ mask,
                                                     unsigned int* __restrict__ ghistA) {
  const int b = blockIdx.x / NSLICE;
  const int sl = blockIdx.x % NSLICE;
  const int t = threadIdx.x;
  __shared__ unsigned int hist[512];
  hist[t] = 0; hist[t + 256] = 0;
  __syncthreads();
  const float4* xi4 = (const float4*)(inp + (size_t)b * HWN);
  const float4* xt4 = (const float4*)(tgt + (size_t)b * HWN);
  const unsigned int* m4 = (const unsigned int*)(mask + (size_t)b * HWN);
  const int per4 = (HWN / NSLICE) / 4;  // 4800
  const int s0 = sl * per4;
  for (int i = s0 + t; i < s0 + per4; i += 256) {
    unsigned int mm = m4[i];
    if (!mm) continue;
    float4 a = xi4[i], c = xt4[i];
    if (mm & 0x000000FFu) { atomicAdd(&hist[fkey(a.x) >> 24], 1u); atomicAdd(&hist[256 + (fkey(c.x) >> 24)], 1u); }
    if (mm & 0x0000FF00u) { atomicAdd(&hist[fkey(a.y) >> 24], 1u); atomicAdd(&hist[256 + (fkey(c.y) >> 24)], 1u); }
    if (mm & 0x00FF0000u) { atomicAdd(&hist[fkey(a.z) >> 24], 1u); atomicAdd(&hist[256 + (fkey(c.z) >> 24)], 1u); }
    if (mm & 0xFF000000u) { atomicAdd(&hist[fkey(a.w) >> 24], 1u); atomicAdd(&hist[256 + (fkey(c.w) >> 24)], 1u); }
  }
  __syncthreads();
  unsigned int h0 = hist[t], h1 = hist[t + 256];
  if (h0) atomicAdd(&ghistA[(b * 2 + 0) * 256 + t], h0);
  if (h1) atomicAdd(&ghistA[(b * 2 + 1) * 256 + t], h1);
}

// ---------- K5b: select level-1 digit ----------
__global__ __launch_bounds__(64) void gselA_kernel(const unsigned int* __restrict__ ghistA,
                                                   int* __restrict__ selA) {
  const int bs = blockIdx.x;
  if (threadIdx.x != 0) return;
  const unsigned int* gh = ghistA + bs * 256;
  unsigned int n = 0;
  for (int i = 0; i < 256; ++i) n += gh[i];
  int c1 = -1, r1 = 0;
  unsigned int nb = 0;
  if (n > 0) {
    unsigned int r = (n - 1) >> 1, cum = 0;
    int bin = 0;
    for (; bin < 256; ++bin) {
      unsigned int h = gh[bin];
      if (cum + h > r) break;
      cum += h;
    }
    c1 = bin; r1 = (int)(r - cum); nb = cum;
  }
  selA[bs * 4 + 0] = c1;
  selA[bs * 4 + 1] = r1;
  selA[bs * 4 + 2] = (int)n;
  selA[bs * 4 + 3] = (int)nb;
}

// ---------- K5c: level-2 digit histogram ((key>>16)&255) within level-1 digit ----------
__global__ __launch_bounds__(256) void gpassB_kernel(const float* __restrict__ inp,
                                                     const float* __restrict__ tgt,
                                                     const unsigned char* __restrict__ mask,
                                                     const int* __restrict__ selA,
                                                     unsigned int* __restrict__ ghistB) {
  const int b = blockIdx.x / NSLICE;
  const int sl = blockIdx.x % NSLICE;
  const int t = threadIdx.x;
  __shared__ unsigned int hist[512];
  hist[t] = 0; hist[t + 256] = 0;
  __syncthreads();
  const unsigned int c1i = (unsigned int)selA[(b * 2 + 0) * 4];
  const unsigned int c1t = (unsigned int)selA[(b * 2 + 1) * 4];
  const float4* xi4 = (const float4*)(inp + (size_t)b * HWN);
  const float4* xt4 = (const float4*)(tgt + (size_t)b * HWN);
  const unsigned int* m4 = (const unsigned int*)(mask + (size_t)b * HWN);
  const int per4 = (HWN / NSLICE) / 4;
  const int s0 = sl * per4;
  for (int i = s0 + t; i < s0 + per4; i += 256) {
    unsigned int mm = m4[i];
    if (!mm) continue;
    float4 a = xi4[i], c = xt4[i];
    #define GPB(av, cv, bit) \
      if (mm & bit) { \
        unsigned int k = fkey(av); \
        if ((k >> 24) == c1i) atomicAdd(&hist[(k >> 16) & 255u], 1u); \
        unsigned int k2 = fkey(cv); \
        if ((k2 >> 24) == c1t) atomicAdd(&hist[256 + ((k2 >> 16) & 255u)], 1u); \
      }
    GPB(a.x, c.x, 0x000000FFu)
    GPB(a.y, c.y, 0x0000FF00u)
    GPB(a.z, c.z, 0x00FF0000u)
    GPB(a.w, c.w, 0xFF000000u)
    #undef GPB
  }
  __syncthreads();
  unsigned int h0 = hist[t], h1 = hist[t + 256];
  if (h0) atomicAdd(&ghistB[(b * 2 + 0) * 256 + t], h0);
  if (h1) atomicAdd(&ghistB[(b * 2 + 1) * 256 + t], h1);
}

// ---------- K5d: select level-2 digit -> 16-bit prefix ----------
__global__ __launch_bounds__(64) void gselB_kernel(const unsigned int* __restrict__ ghistB,
                                                   const int* __restrict__ selA,
                                                   int* __restrict__ selB) {
  const int bs = blockIdx.x;
  if (threadIdx.x != 0) return;
  const int c1 = selA[bs * 4 + 0];
  const int r1 = selA[bs * 4 + 1];
  const int n = selA[bs * 4 + 2];
  const int nb1 = selA[bs * 4 + 3];
  if (c1 < 0) {
    selB[bs * 4 + 0] = -1;
    selB[bs * 4 + 1] = 0;
    selB[bs * 4 + 2] = 0;
    selB[bs * 4 + 3] = 0;
    return;
  }
  const unsigned int* gh = ghistB + bs * 256;
  unsigned int r = (unsigned int)r1, cum = 0;
  int bin = 0;
  for (; bin < 256; ++bin) {
    unsigned int h = gh[bin];
    if (cum + h > r) break;
    cum += h;
  }
  selB[bs * 4 + 0] = (c1 << 8) | bin;      // 16-bit prefix
  selB[bs * 4 + 1] = (int)(r - cum);       // residual rank among candidates
  selB[bs * 4 + 2] = n;
  selB[bs * 4 + 3] = nb1 + (int)cum;       // # elements strictly below prefix
}

// ---------- K5e: collect candidates + below/above sums (vectorized) ----------
__global__ __launch_bounds__(256) void gcollect_kernel(const float* __restrict__ inp,
                                                       const float* __restrict__ tgt,
                                                       const unsigned char* __restrict__ mask,
                                                       const int* __restrict__ selB,
                                                       float* __restrict__ cand,
                                                       unsigned int* __restrict__ ccount,
                                                       float* __restrict__ sbelow,
                                                       float* __restrict__ sabove) {
  const int bs = blockIdx.x / NSLICE;
  const int sl = blockIdx.x % NSLICE;
  const int b = bs >> 1, s = bs & 1;
  const float* x = (s == 0 ? inp : tgt) + (size_t)b * HWN;
  const unsigned char* m = mask + (size_t)b * HWN;
  const int prefix = selB[bs * 4 + 0];
  __shared__ float red[512];
  __shared__ float buf[LCAP];
  __shared__ unsigned int lcnt, gbase;
  const int t = threadIdx.x;
  if (t == 0) lcnt = 0;
  __syncthreads();
  float sb = 0.f, sa = 0.f;
  if (prefix >= 0) {
    float* cd = cand + (size_t)bs * CAP;
    const float4* x4 = (const float4*)x;
    const unsigned int* m4 = (const unsigned int*)m;
    const int per4 = (HWN / NSLICE) / 4;
    const int s0 = sl * per4;
    for (int i = s0 + t; i < s0 + per4; i += 256) {
      unsigned int mm = m4[i];
      if (!mm) continue;
      float4 a = x4[i];
      #define GCOL(av, bit) \
        if (mm & bit) { \
          float v = av; \
          int pf = (int)(fkey(v) >> 16); \
          if (pf < prefix) sb += v; \
          else if (pf > prefix) sa += v; \
          else { \
            unsigned int pos = atomicAdd(&lcnt, 1u); \
            if (pos < LCAP) buf[pos] = v; \
            else { \
              unsigned int g = atomicAdd(&ccount[bs * CPAD], 1u); \
              if (g < CAP) cd[g] = v; \
            } \
          } \
        }
      GCOL(a.x, 0x000000FFu)
      GCOL(a.y, 0x0000FF00u)
      GCOL(a.z, 0x00FF0000u)
      GCOL(a.w, 0xFF000000u)
      #undef GCOL
    }
  }
  __syncthreads();
  if (prefix >= 0) {
    unsigned int c = min(lcnt, (unsigned int)LCAP);
    if (t == 0 && c > 0) gbase = atomicAdd(&ccount[bs * CPAD], c);
    __syncthreads();
    if (c > 0) {
      float* cd = cand + (size_t)bs * CAP;
      unsigned int base = gbase;
      for (unsigned int i = t; i < c; i += 256) {
        unsigned int pos = base + i;
        if (pos < CAP) cd[pos] = buf[i];
      }
    }
  }
  float2 ts = breduce256x2(sb, sa, red);
  if (t == 0) {
    atomicAdd(&sbelow[bs], ts.x);
    atomicAdd(&sabove[bs], ts.y);
  }
}

// ---------- K5f: exact select among candidates (low 16 bits) + scale ----------
__global__ __launch_bounds__(256) void gfinal_kernel(const float* __restrict__ cand,
                                                     const unsigned int* __restrict__ ccount,
                                                     const int* __restrict__ selB,
                                                     const float* __restrict__ sbelow,
                                                     const float* __restrict__ sabove,
                                                     float* __restrict__ gstats,
                                                     float* __restrict__ nvals) {
  const int bs = blockIdx.x;
  const int t = threadIdx.x;
  const int prefix = selB[bs * 4 + 0];
  const int r2 = selB[bs * 4 + 1];
  const int n = selB[bs * 4 + 2];
  const int nbelow = selB[bs * 4 + 3];
  __shared__ unsigned int hist[256];
  __shared__ float red[256];
  __shared__ int sh_bin1, sh_r3;
  const float* cd = cand + (size_t)bs * CAP;
  int c = (int)min(ccount[bs * CPAD], (unsigned int)CAP);
  if (prefix < 0) {
    if (t == 0) {
      gstats[bs * 2 + 0] = 0.f;
      gstats[bs * 2 + 1] = 0.f;
      if ((bs & 1) == 0) nvals[bs >> 1] = 0.f;
    }
    return;
  }

  // pass 1: bits [15:8]
  hist[t] = 0;
  __syncthreads();
  for (int i = t; i < c; i += 256)
    atomicAdd(&hist[(fkey(cd[i]) >> 8) & 255u], 1u);
  __syncthreads();
  if (t == 0) {
    unsigned int rr = (unsigned int)r2, cum = 0;
    int bin = 0;
    for (; bin < 256; ++bin) {
      unsigned int h = hist[bin];
      if (cum + h > rr) break;
      cum += h;
    }
    sh_bin1 = bin;
    sh_r3 = (int)(rr - cum);
  }
  __syncthreads();
  const int bin1 = sh_bin1;
  const int r3 = sh_r3;

  // pass 2: bits [7:0]
  hist[t] = 0;
  __syncthreads();
  for (int i = t; i < c; i += 256) {
    unsigned int key = fkey(cd[i]);
    if (((key >> 8) & 255u) == (unsigned int)bin1)
      atomicAdd(&hist[key & 255u], 1u);
  }
  __syncthreads();
  __shared__ float sh_med;
  if (t == 0) {
    unsigned int rr = (unsigned int)r3, cum = 0;
    int bin = 0;
    for (; bin < 256; ++bin) {
      unsigned int h = hist[bin];
      if (cum + h > rr) break;
      cum += h;
    }
    unsigned int key = ((unsigned int)prefix << 16) |
                       ((unsigned int)bin1 << 8) | (unsigned int)bin;
    sh_med = fkey_inv(key);
  }
  __syncthreads();
  const float med = sh_med;

  float ps = 0.f;
  for (int i = t; i < c; i += 256) ps += fabsf(cd[i] - med);
  float scand = breduce256(ps, red);
  if (t == 0) {
    float nb = (float)nbelow;
    float na = (float)(n - nbelow - c);
    float num = (nb * med - sbelow[bs]) + (sabove[bs] - na * med) + scand;
    gstats[bs * 2 + 0] = med;
    gstats[bs * 2 + 1] = num / fmaxf((float)n, 1.f);
    if ((bs & 1) == 0) nvals[bs >> 1] = (float)n;
  }
}

// ---------- K6a: global error partial sums (vectorized, both signals) ----------
__global__ __launch_bounds__(256) void gerr_kernel(const float* __restrict__ inp,
                                                   const float* __restrict__ tgt,
                                                   const unsigned char* __restrict__ mask,
                                                   const float* __restrict__ gstats,
                                                   float* __restrict__ gacc) {
  const int b = blockIdx.x / NSLICE;
  const int sl = blockIdx.x % NSLICE;
  __shared__ float red[256];
  const int t = threadIdx.x;
  const float med_i = gstats[(b * 2 + 0) * 2 + 0];
  const float sc_i = fmaxf(gstats[(b * 2 + 0) * 2 + 1], EPSV);
  const float med_t = gstats[(b * 2 + 1) * 2 + 0];
  const float sc_t = fmaxf(gstats[(b * 2 + 1) * 2 + 1], EPSV);
  const float ri = 1.f / sc_i, rt = 1.f / sc_t;
  const float4* xi4 = (const float4*)(inp + (size_t)b * HWN);
  const float4* xt4 = (const float4*)(tgt + (size_t)b * HWN);
  const unsigned int* m4 = (const unsigned int*)(mask + (size_t)b * HWN);
  const int per4 = (HWN / NSLICE) / 4;
  const int s0 = sl * per4;
  float part = 0.f;
  for (int i = s0 + t; i < s0 + per4; i += 256) {
    unsigned int mm = m4[i];
    if (!mm) continue;
    float4 a = xi4[i], c = xt4[i];
    if (mm & 0x000000FFu) part += fmaxf(fabsf((a.x - med_i) * ri - (c.x - med_t) * rt), EPSV);
    if (mm & 0x0000FF00u) part += fmaxf(fabsf((a.y - med_i) * ri - (c.y - med_t) * rt), EPSV);
    if (mm & 0x00FF0000u) part += fmaxf(fabsf((a.z - med_i) * ri - (c.z - med_t) * rt), EPSV);
    if (mm & 0xFF000000u) part += fmaxf(fabsf((a.w - med_i) * ri - (c.w - med_t) * rt), EPSV);
  }
  float tp = breduce256(part, red);
  if (t == 0) atomicAdd(&gacc[b], tp);
}

// ---------- K6b: combine ----------
__global__ __launch_bounds__(64) void final_kernel(const float* __restrict__ gacc,
                                                   const float* __restrict__ nvals,
                                                   const float* __restrict__ e_patch,
                                                   float* __restrict__ out) {
  const int b = threadIdx.x;
  if (b < BB) {
    float n = nvals[b];
    float eg = sqrtf(fmaxf(gacc[b] / fmaxf(n, 1.f), EPSV));
    out[b] = 0.5f * (e_patch[b] + eg);
  }
}

extern "C" void kernel_launch(void* const* d_in, const int* in_sizes, int n_in,
                              void* d_out, int out_size, void* d_ws, size_t ws_size,
                              hipStream_t stream) {
  const float* inp = (const float*)d_in[0];
  const float* tgt = (const float*)d_in[1];
  const unsigned char* mask = (const unsigned char*)d_in[2];   // jax bool -> 1 byte
  const float* image = (const float*)d_in[3];
  const unsigned char* vmask = (const unsigned char*)d_in[4];  // jax bool -> 1 byte
  float* out = (float*)d_out;

  float* ws = (float*)d_ws;
  float* re = ws;                                   // 48960
  int* coords = (int*)(ws + 48960);                 // 9792
  float* ep = ws + 48960 + 9792;                    // 4896
  float* val = ep + 4896;                           // 4896
  float* e_patch = val + 4896;                      // 32
  float* gstats = e_patch + 32;                     // 128
  float* nvals = gstats + 128;                      // 32
  int* selA = (int*)(nvals + 32);                   // 256
  int* selB = selA + 256;                           // 256
  float* cand = (float*)(selB + 256);               // 64*CAP = 1,048,576
  // zeroed region (one contiguous memset)
  unsigned int* ghistA = (unsigned int*)(cand + (size_t)64 * CAP);  // 64*256
  unsigned int* ghistB = ghistA + 64 * 256;                         // 64*256
  unsigned int* ccount = ghistB + 64 * 256;                         // 64*CPAD
  float* sbelow = (float*)(ccount + 64 * CPAD);                     // 64
  float* sabove = sbelow + 64;                                      // 64
  float* gacc = sabove + 64;                                        // 32
  size_t zero_bytes = ((size_t)64 * 256 * 2 + 64 * CPAD + 64 + 64 + 32) * 4;
  hipMemsetAsync(ghistA, 0, zero_bytes, stream);

  // rpart (BB*TSLICE*OHW = 489,600 ints) aliases cand: topk finishes before
  // gcollect writes cand (stream-ordered), and coords is consumed by patch.
  int* rpart = (int*)cand;

  edge_resize_kernel<<<(BB * OHW + 255) / 256, 256, 0, stream>>>(image, vmask, re);
  topk_rank_kernel<<<BB * TSLICE, 256, 0, stream>>>(re, rpart);
  topk_write_kernel<<<BB, 256, 0, stream>>>(rpart, coords);
  patch_kernel<<<BB * KTOP, 256, 0, stream>>>(inp, tgt, mask, coords, ep, val);
  preduce_kernel<<<BB, 256, 0, stream>>>(ep, val, e_patch);
  gpassA_kernel<<<BB * NSLICE, 256, 0, stream>>>(inp, tgt, mask, ghistA);
  gselA_kernel<<<BB * 2, 64, 0, stream>>>(ghistA, selA);
  gpassB_kernel<<<BB * NSLICE, 256, 0, stream>>>(inp, tgt, mask, selA, ghistB);
  gselB_kernel<<<BB * 2, 64, 0, stream>>>(ghistB, selA, selB);
  gcollect_kernel<<<BB * 2 * NSLICE, 256, 0, stream>>>(inp, tgt, mask, selB, cand, ccount, sbelow, sabove);
  gfinal_kernel<<<BB * 2, 256, 0, stream>>>(cand, ccount, selB, sbelow, sabove, gstats, nvals);
  gerr_kernel<<<BB * NSLICE, 256, 0, stream>>>(inp, tgt, mask, gstats, gacc);
  final_kernel<<<1, 64, 0, stream>>>(gacc, nvals, e_patch, out);
}

// Round 7
// 427.007 us; speedup vs baseline: 5.4061x; 1.0571x over previous
//
#include <hip/hip_runtime.h>
#include <math.h>

// Problem constants (fixed by setup_inputs: B=32, H=480, W=640)
#define BB 32
#define HH 480
#define WW 640
#define HWN (HH * WW)
#define OH 34            // H // RESHAPE
#define OW 45            // W // RESHAPE
#define OHW (OH * OW)    // 1530
#define KTOP 153         // max(int(0.1*oh*ow), 10)
#define KS 25            // kernel size (odd)
#define PHW 12           // half kernel
#define PATCH (KS * KS)  // 625
#define RESHAPE_I 14
#define EPSV 1e-5f

// top-k machinery
#define TSLICE 10
#define TSW (OHW / TSLICE)   // 153 j's per slice

// global-median machinery: two 8-bit radix levels (256 bins each)
#define PSLICE 32        // WGs per batch for histogram/error passes
#define NSLICE 16        // WGs per (b,s) for collect pass
#define CAP 16384        // candidate cap per (b,s)
#define LCAP 2048        // per-WG LDS candidate buffer (expected ~40 used)
#define CPAD 32          // ccount stride in uints (128 B -> no false sharing)

// ---------- monotone float <-> uint key ----------
__device__ __forceinline__ unsigned int fkey(float f) {
  unsigned int u = __float_as_uint(f);
  return (u & 0x80000000u) ? ~u : (u | 0x80000000u);
}
__device__ __forceinline__ float fkey_inv(unsigned int k) {
  unsigned int u = (k & 0x80000000u) ? (k & 0x7FFFFFFFu) : ~k;
  return __uint_as_float(u);
}

// ---------- 256-thread block reduce (single) ----------
__device__ __forceinline__ float breduce256(float v, float* red) {
  const int t = threadIdx.x;
  __syncthreads();
  red[t] = v;
  __syncthreads();
  for (int s2 = 128; s2 > 0; s2 >>= 1) {
    if (t < s2) red[t] += red[t + s2];
    __syncthreads();
  }
  float r = red[0];
  __syncthreads();
  return r;
}

// ---------- 256-thread block reduce (pair) ----------
__device__ __forceinline__ float2 breduce256x2(float a, float b, float* red) {
  const int t = threadIdx.x;
  __syncthreads();
  red[t] = a;
  red[256 + t] = b;
  __syncthreads();
  for (int s2 = 128; s2 > 0; s2 >>= 1) {
    if (t < s2) {
      red[t] += red[t + s2];
      red[256 + t] += red[256 + t + s2];
    }
    __syncthreads();
  }
  float2 r = make_float2(red[0], red[256]);
  __syncthreads();
  return r;
}

// ---------- edge value at (b, y, x): sobel + erode(validity) + border mask ----------
__device__ float edge_at(const float* __restrict__ image, const unsigned char* __restrict__ vmask,
                         int b, int y, int x) {
  if (y < 3 || y >= HH - 3 || x < 3 || x >= WW - 3) return 0.f;
  const unsigned char* vm = vmask + (size_t)b * HWN;
  #pragma unroll
  for (int dy = -1; dy <= 1; ++dy) {
    #pragma unroll
    for (int dx = -1; dx <= 1; ++dx) {
      if (!vm[(size_t)(y + dy) * WW + (x + dx)]) return 0.f;
    }
  }
  const float* img = image + (size_t)b * 3 * HWN;
  float sx2 = 0.f, sy2 = 0.f;
  #pragma unroll
  for (int c = 0; c < 3; ++c) {
    const float* p = img + (size_t)c * HWN + (size_t)y * WW + x;
    float a00 = p[-WW - 1], a01 = p[-WW], a02 = p[-WW + 1];
    float a10 = p[-1],                    a12 = p[1];
    float a20 = p[WW - 1],  a21 = p[WW],  a22 = p[WW + 1];
    float gx = (-a00 + a02 + -2.f * a10 + 2.f * a12 + -a20 + a22) / 8.f;
    float gy = (-a00 + -2.f * a01 + -a02 + a20 + 2.f * a21 + a22) / 8.f;
    sx2 += gx * gx;
    sy2 += gy * gy;
  }
  float gxm = sqrtf(sx2 / 3.f);
  float gym = sqrtf(sy2 / 3.f);
  return sqrtf(gxm * gxm + gym * gym);
}

// ---------- K1: fused edge + bilinear resize, corner-parallel ----------
// One thread per (cell, corner): 4x parallelism vs per-cell; corner terms
// combined via shfl_xor butterflies (lanes 4c..4c+3 in one wave).
// BB*OHW*4 = 195840 = 765 * 256 exactly.
__global__ __launch_bounds__(256) void edge_resize_kernel(const float* __restrict__ image,
                                                          const unsigned char* __restrict__ vmask,
                                                          float* __restrict__ re) {
  int gid = blockIdx.x * 256 + threadIdx.x;
  int corner = gid & 3;
  int cell = gid >> 2;
  int b = cell / OHW;
  int rem = cell % OHW;
  int oy = rem / OW, ox = rem % OW;

  const float ry = (float)((double)HH / (double)OH);
  const float rx = (float)((double)WW / (double)OW);
  float cy = fminf(fmaxf(((float)oy + 0.5f) * ry - 0.5f, 0.f), (float)(HH - 1));
  float cx = fminf(fmaxf(((float)ox + 0.5f) * rx - 0.5f, 0.f), (float)(WW - 1));
  int y0 = (int)floorf(cy);
  int x0 = (int)floorf(cx);
  int y1 = min(y0 + 1, HH - 1);
  int x1 = min(x0 + 1, WW - 1);
  float wy = cy - (float)y0;
  float wx = cx - (float)x0;

  int yy = (corner & 2) ? y1 : y0;
  int xx = (corner & 1) ? x1 : x0;
  float w = ((corner & 2) ? wy : 1.f - wy) * ((corner & 1) ? wx : 1.f - wx);
  float g = edge_at(image, vmask, b, yy, xx) * w;
  g += __shfl_xor(g, 1, 64);
  g += __shfl_xor(g, 2, 64);
  if (corner == 0) re[cell] = g;
}

// ---------- K2a: partial ranks over j-slices ----------
__global__ __launch_bounds__(256) void topk_rank_kernel(const float* __restrict__ re,
                                                        int* __restrict__ rpart) {
  const int b = blockIdx.x / TSLICE;
  const int sl = blockIdx.x % TSLICE;
  const int t = threadIdx.x;
  __shared__ float e[OHW];
  for (int i = t; i < OHW; i += 256) e[i] = re[b * OHW + i];
  __syncthreads();

  float vi[6];
  int idx[6], cnt[6];
  #pragma unroll
  for (int q = 0; q < 6; ++q) {
    int i = t + q * 256;
    idx[q] = i;
    vi[q] = (i < OHW) ? e[i] : 0.f;
    cnt[q] = 0;
  }
  const int j0 = sl * TSW;
  for (int jj = 0; jj < TSW; ++jj) {
    int j = j0 + jj;
    float u = e[j];  // broadcast
    #pragma unroll
    for (int q = 0; q < 6; ++q) {
      cnt[q] += (u > vi[q]) || (u == vi[q] && j < idx[q]);
    }
  }
  int* rp = rpart + ((size_t)b * TSLICE + sl) * OHW;
  #pragma unroll
  for (int q = 0; q < 6; ++q) {
    if (idx[q] < OHW) rp[idx[q]] = cnt[q];
  }
}

// ---------- K2b: sum partial ranks, scatter coords ----------
__global__ __launch_bounds__(256) void topk_write_kernel(const int* __restrict__ rpart,
                                                         int* __restrict__ coords) {
  const int b = blockIdx.x;
  const int t = threadIdx.x;
  const int* rp = rpart + (size_t)b * TSLICE * OHW;
  for (int i = t; i < OHW; i += 256) {
    int rank = 0;
    #pragma unroll
    for (int sl = 0; sl < TSLICE; ++sl) rank += rp[sl * OHW + i];
    if (rank < KTOP) {
      coords[(b * KTOP + rank) * 2 + 0] = (i / OW) * RESHAPE_I;
      coords[(b * KTOP + rank) * 2 + 1] = (i % OW) * RESHAPE_I;
    }
  }
}

// ---------- K3: per-patch SSI error, single wave64 per patch ----------
// 10 elems/lane in registers; 4-pass 8-bit radix select with wave-shfl scan
// (bit-exact vs sort[r]); all reductions via shfl_xor butterflies.
__global__ __launch_bounds__(64) void patch_kernel(const float* __restrict__ inp,
                                                   const float* __restrict__ tgt,
                                                   const unsigned char* __restrict__ mask,
                                                   const int* __restrict__ coords,
                                                   float* __restrict__ ep, float* __restrict__ val) {
  const int bk = blockIdx.x;
  const int b = bk / KTOP;
  const int t = threadIdx.x;
  __shared__ unsigned int hist[512];   // [0:256) in, [256:512) tg
  __shared__ unsigned int sh_pref[2];
  __shared__ int sh_rank[2];

  const int cy = coords[bk * 2 + 0];
  const int cx = coords[bk * 2 + 1];

  float v_in[10], v_tg[10];
  unsigned int k_in[10], k_tg[10];
  unsigned int mbits = 0;
  #pragma unroll
  for (int q = 0; q < 10; ++q) {
    int i = t + q * 64;
    float vi = 0.f, vt = 0.f;
    if (i < PATCH) {
      int dy = i / KS - PHW, dx = i % KS - PHW;
      int y = cy + dy, x = cx + dx;
      if (y >= 0 && y < HH && x >= 0 && x < WW) {
        size_t off = (size_t)b * HWN + (size_t)y * WW + x;
        if (mask[off]) mbits |= (1u << q);
        vi = inp[off];
        vt = tgt[off];
      }
    }
    v_in[q] = vi; v_tg[q] = vt;
    k_in[q] = fkey(vi); k_tg[q] = fkey(vt);
  }

  // n = masked count (wave butterfly)
  int pn = __popc(mbits);
  #pragma unroll
  for (int d = 32; d > 0; d >>= 1) pn += __shfl_xor(pn, d, 64);
  const int n = pn;
  const float nf = (float)n;
  const int r = (n > 0) ? ((n - 1) >> 1) : 0;

  if (t == 0) {
    sh_pref[0] = 0; sh_pref[1] = 0;
    sh_rank[0] = r; sh_rank[1] = r;
  }
  __syncthreads();

  #pragma unroll
  for (int p = 0; p < 4; ++p) {
    const int shift = 24 - 8 * p;
    #pragma unroll
    for (int j = 0; j < 8; ++j) hist[t + 64 * j] = 0;
    __syncthreads();
    const int r_in = sh_rank[0], r_tg = sh_rank[1];
    const unsigned int pref_in = sh_pref[0], pref_tg = sh_pref[1];
    #pragma unroll
    for (int q = 0; q < 10; ++q) {
      if (mbits & (1u << q)) {
        unsigned int k = k_in[q];
        if (p == 0 || (k >> (shift + 8)) == pref_in)
          atomicAdd(&hist[(k >> shift) & 255u], 1u);
        unsigned int k2 = k_tg[q];
        if (p == 0 || (k2 >> (shift + 8)) == pref_tg)
          atomicAdd(&hist[256 + ((k2 >> shift) & 255u)], 1u);
      }
    }
    __syncthreads();
    // wave-scan descent, both signals: lane t owns bins 4t..4t+3
    {
      unsigned int a0 = hist[t * 4 + 0], a1 = hist[t * 4 + 1];
      unsigned int a2 = hist[t * 4 + 2], a3 = hist[t * 4 + 3];
      unsigned int b0 = hist[256 + t * 4 + 0], b1 = hist[256 + t * 4 + 1];
      unsigned int b2 = hist[256 + t * 4 + 2], b3 = hist[256 + t * 4 + 3];
      unsigned int sa0 = a0, sa1 = sa0 + a1, sa2 = sa1 + a2, sa3 = sa2 + a3;
      unsigned int sb0 = b0, sb1 = sb0 + b1, sb2 = sb1 + b2, sb3 = sb2 + b3;
      unsigned int ta = sa3, tb = sb3;
      #pragma unroll
      for (int d = 1; d < 64; d <<= 1) {
        unsigned int ua = (unsigned int)__shfl_up((int)ta, d, 64);
        unsigned int ub = (unsigned int)__shfl_up((int)tb, d, 64);
        if (t >= d) { ta += ua; tb += ub; }
      }
      unsigned int exa = ta - sa3, exb = tb - sb3;
      unsigned int rra = (unsigned int)r_in, rrb = (unsigned int)r_tg;
      unsigned int pa[4] = {exa, exa + sa0, exa + sa1, exa + sa2};
      unsigned int ca[4] = {exa + sa0, exa + sa1, exa + sa2, exa + sa3};
      unsigned int pb[4] = {exb, exb + sb0, exb + sb1, exb + sb2};
      unsigned int cb[4] = {exb + sb0, exb + sb1, exb + sb2, exb + sb3};
      #pragma unroll
      for (int j = 0; j < 4; ++j) {
        if (rra >= pa[j] && rra < ca[j]) {
          sh_pref[0] = (pref_in << 8) | (unsigned int)(t * 4 + j);
          sh_rank[0] = (int)(rra - pa[j]);
        }
        if (rrb >= pb[j] && rrb < cb[j]) {
          sh_pref[1] = (pref_tg << 8) | (unsigned int)(t * 4 + j);
          sh_rank[1] = (int)(rrb - pb[j]);
        }
      }
    }
    __syncthreads();
  }

  const float med_i = (n > 0) ? fkey_inv(sh_pref[0]) : 0.f;
  const float med_t = (n > 0) ? fkey_inv(sh_pref[1]) : 0.f;

  // masked mean abs deviation (wave butterflies)
  float pi = 0.f, pt = 0.f;
  #pragma unroll
  for (int q = 0; q < 10; ++q) {
    if (mbits & (1u << q)) {
      pi += fabsf(v_in[q] - med_i);
      pt += fabsf(v_tg[q] - med_t);
    }
  }
  #pragma unroll
  for (int d = 32; d > 0; d >>= 1) {
    pi += __shfl_xor(pi, d, 64);
    pt += __shfl_xor(pt, d, 64);
  }
  const float si = fmaxf(pi / fmaxf(nf, 1.f), EPSV);
  const float st = fmaxf(pt / fmaxf(nf, 1.f), EPSV);

  float pe = 0.f;
  #pragma unroll
  for (int q = 0; q < 10; ++q) {
    if (mbits & (1u << q)) {
      float a = (v_in[q] - med_i) / si;
      float c = (v_tg[q] - med_t) / st;
      pe += fmaxf(fabsf(a - c), EPSV);
    }
  }
  #pragma unroll
  for (int d = 32; d > 0; d >>= 1) pe += __shfl_xor(pe, d, 64);

  if (t == 0) {
    ep[bk] = sqrtf(fmaxf(pe / fmaxf(nf, 1.f), EPSV));
    val[bk] = (n >= 4) ? 1.f : 0.f;
  }
}

// ---------- K4: e_patch[b] ----------
__global__ __launch_bounds__(256) void preduce_kernel(const float* __restrict__ ep,
                                                      const float* __restrict__ val,
                                                      float* __restrict__ e_patch) {
  const int b = blockIdx.x;
  const int t = threadIdx.x;
  __shared__ float red[512];
  float se = 0.f, sv = 0.f;
  for (int i = t; i < KTOP; i += 256) {
    float v = val[b * KTOP + i];
    se += ep[b * KTOP + i] * v;
    sv += v;
  }
  float2 tt = breduce256x2(se, sv, red);
  if (t == 0) e_patch[b] = tt.x / fmaxf(tt.y, 1.f);
}

// ---------- K5a: level-1 digit histogram (key>>24), both signals ----------
__global__ __launch_bounds__(256) void gpassA_kernel(const float* __restrict__ inp,
                                                     const float* __restrict__ tgt,
                                                     const unsigned char* __restrict__ mask,
                                                     unsigned int* __restrict__ ghistA) {
  const int b = blockIdx.x / PSLICE;
  const int sl = blockIdx.x % PSLICE;
  const int t = threadIdx.x;
  __shared__ unsigned int hist[512];
  hist[t] = 0; hist[t + 256] = 0;
  __syncthreads();
  const float4* xi4 = (const float4*)(inp + (size_t)b * HWN);
  const float4* xt4 = (const float4*)(tgt + (size_t)b * HWN);
  const unsigned int* m4 = (const unsigned int*)(mask + (size_t)b * HWN);
  const int per4 = (HWN / PSLICE) / 4;  // 2400
  const int s0 = sl * per4;
  for (int i = s0 + t; i < s0 + per4; i += 256) {
    unsigned int mm = m4[i];
    if (!mm) continue;
    float4 a = xi4[i], c = xt4[i];
    if (mm & 0x000000FFu) { atomicAdd(&hist[fkey(a.x) >> 24], 1u); atomicAdd(&hist[256 + (fkey(c.x) >> 24)], 1u); }
    if (mm & 0x0000FF00u) { atomicAdd(&hist[fkey(a.y) >> 24], 1u); atomicAdd(&hist[256 + (fkey(c.y) >> 24)], 1u); }
    if (mm & 0x00FF0000u) { atomicAdd(&hist[fkey(a.z) >> 24], 1u); atomicAdd(&hist[256 + (fkey(c.z) >> 24)], 1u); }
    if (mm & 0xFF000000u) { atomicAdd(&hist[fkey(a.w) >> 24], 1u); atomicAdd(&hist[256 + (fkey(c.w) >> 24)], 1u); }
  }
  __syncthreads();
  unsigned int h0 = hist[t], h1 = hist[t + 256];
  if (h0) atomicAdd(&ghistA[(b * 2 + 0) * 256 + t], h0);
  if (h1) atomicAdd(&ghistA[(b * 2 + 1) * 256 + t], h1);
}

// ---------- K5b: select level-1 digit ----------
__global__ __launch_bounds__(64) void gselA_kernel(const unsigned int* __restrict__ ghistA,
                                                   int* __restrict__ selA) {
  const int bs = blockIdx.x;
  if (threadIdx.x != 0) return;
  const unsigned int* gh = ghistA + bs * 256;
  unsigned int n = 0;
  for (int i = 0; i < 256; ++i) n += gh[i];
  int c1 = -1, r1 = 0;
  unsigned int nb = 0;
  if (n > 0) {
    unsigned int r = (n - 1) >> 1, cum = 0;
    int bin = 0;
    for (; bin < 256; ++bin) {
      unsigned int h = gh[bin];
      if (cum + h > r) break;
      cum += h;
    }
    c1 = bin; r1 = (int)(r - cum); nb = cum;
  }
  selA[bs * 4 + 0] = c1;
  selA[bs * 4 + 1] = r1;
  selA[bs * 4 + 2] = (int)n;
  selA[bs * 4 + 3] = (int)nb;
}

// ---------- K5c: level-2 digit histogram ((key>>16)&255) within level-1 digit ----------
__global__ __launch_bounds__(256) void gpassB_kernel(const float* __restrict__ inp,
                                                     const float* __restrict__ tgt,
                                                     const unsigned char* __restrict__ mask,
                                                     const int* __restrict__ selA,
                                                     unsigned int* __restrict__ ghistB) {
  const int b = blockIdx.x / PSLICE;
  const int sl = blockIdx.x % PSLICE;
  const int t = threadIdx.x;
  __shared__ unsigned int hist[512];
  hist[t] = 0; hist[t + 256] = 0;
  __syncthreads();
  const unsigned int c1i = (unsigned int)selA[(b * 2 + 0) * 4];
  const unsigned int c1t = (unsigned int)selA[(b * 2 + 1) * 4];
  const float4* xi4 = (const float4*)(inp + (size_t)b * HWN);
  const float4* xt4 = (const float4*)(tgt + (size_t)b * HWN);
  const unsigned int* m4 = (const unsigned int*)(mask + (size_t)b * HWN);
  const int per4 = (HWN / PSLICE) / 4;
  const int s0 = sl * per4;
  for (int i = s0 + t; i < s0 + per4; i += 256) {
    unsigned int mm = m4[i];
    if (!mm) continue;
    float4 a = xi4[i], c = xt4[i];
    #define GPB(av, cv, bit) \
      if (mm & bit) { \
        unsigned int k = fkey(av); \
        if ((k >> 24) == c1i) atomicAdd(&hist[(k >> 16) & 255u], 1u); \
        unsigned int k2 = fkey(cv); \
        if ((k2 >> 24) == c1t) atomicAdd(&hist[256 + ((k2 >> 16) & 255u)], 1u); \
      }
    GPB(a.x, c.x, 0x000000FFu)
    GPB(a.y, c.y, 0x0000FF00u)
    GPB(a.z, c.z, 0x00FF0000u)
    GPB(a.w, c.w, 0xFF000000u)
    #undef GPB
  }
  __syncthreads();
  unsigned int h0 = hist[t], h1 = hist[t + 256];
  if (h0) atomicAdd(&ghistB[(b * 2 + 0) * 256 + t], h0);
  if (h1) atomicAdd(&ghistB[(b * 2 + 1) * 256 + t], h1);
}

// ---------- K5d: select level-2 digit -> 16-bit prefix ----------
__global__ __launch_bounds__(64) void gselB_kernel(const unsigned int* __restrict__ ghistB,
                                                   const int* __restrict__ selA,
                                                   int* __restrict__ selB) {
  const int bs = blockIdx.x;
  if (threadIdx.x != 0) return;
  const int c1 = selA[bs * 4 + 0];
  const int r1 = selA[bs * 4 + 1];
  const int n = selA[bs * 4 + 2];
  const int nb1 = selA[bs * 4 + 3];
  if (c1 < 0) {
    selB[bs * 4 + 0] = -1;
    selB[bs * 4 + 1] = 0;
    selB[bs * 4 + 2] = 0;
    selB[bs * 4 + 3] = 0;
    return;
  }
  const unsigned int* gh = ghistB + bs * 256;
  unsigned int r = (unsigned int)r1, cum = 0;
  int bin = 0;
  for (; bin < 256; ++bin) {
    unsigned int h = gh[bin];
    if (cum + h > r) break;
    cum += h;
  }
  selB[bs * 4 + 0] = (c1 << 8) | bin;      // 16-bit prefix
  selB[bs * 4 + 1] = (int)(r - cum);       // residual rank among candidates
  selB[bs * 4 + 2] = n;
  selB[bs * 4 + 3] = nb1 + (int)cum;       // # elements strictly below prefix
}

// ---------- K5e: collect candidates + below/above sums (vectorized) ----------
__global__ __launch_bounds__(256) void gcollect_kernel(const float* __restrict__ inp,
                                                       const float* __restrict__ tgt,
                                                       const unsigned char* __restrict__ mask,
                                                       const int* __restrict__ selB,
                                                       float* __restrict__ cand,
                                                       unsigned int* __restrict__ ccount,
                                                       float* __restrict__ sbelow,
                                                       float* __restrict__ sabove) {
  const int bs = blockIdx.x / NSLICE;
  const int sl = blockIdx.x % NSLICE;
  const int b = bs >> 1, s = bs & 1;
  const float* x = (s == 0 ? inp : tgt) + (size_t)b * HWN;
  const unsigned char* m = mask + (size_t)b * HWN;
  const int prefix = selB[bs * 4 + 0];
  __shared__ float red[512];
  __shared__ float buf[LCAP];
  __shared__ unsigned int lcnt, gbase;
  const int t = threadIdx.x;
  if (t == 0) lcnt = 0;
  __syncthreads();
  float sb = 0.f, sa = 0.f;
  if (prefix >= 0) {
    float* cd = cand + (size_t)bs * CAP;
    const float4* x4 = (const float4*)x;
    const unsigned int* m4 = (const unsigned int*)m;
    const int per4 = (HWN / NSLICE) / 4;
    const int s0 = sl * per4;
    for (int i = s0 + t; i < s0 + per4; i += 256) {
      unsigned int mm = m4[i];
      if (!mm) continue;
      float4 a = x4[i];
      #define GCOL(av, bit) \
        if (mm & bit) { \
          float v = av; \
          int pf = (int)(fkey(v) >> 16); \
          if (pf < prefix) sb += v; \
          else if (pf > prefix) sa += v; \
          else { \
            unsigned int pos = atomicAdd(&lcnt, 1u); \
            if (pos < LCAP) buf[pos] = v; \
            else { \
              unsigned int g = atomicAdd(&ccount[bs * CPAD], 1u); \
              if (g < CAP) cd[g] = v; \
            } \
          } \
        }
      GCOL(a.x, 0x000000FFu)
      GCOL(a.y, 0x0000FF00u)
      GCOL(a.z, 0x00FF0000u)
      GCOL(a.w, 0xFF000000u)
      #undef GCOL
    }
  }
  __syncthreads();
  if (prefix >= 0) {
    unsigned int c = min(lcnt, (unsigned int)LCAP);
    if (t == 0 && c > 0) gbase = atomicAdd(&ccount[bs * CPAD], c);
    __syncthreads();
    if (c > 0) {
      float* cd = cand + (size_t)bs * CAP;
      unsigned int base = gbase;
      for (unsigned int i = t; i < c; i += 256) {
        unsigned int pos = base + i;
        if (pos < CAP) cd[pos] = buf[i];
      }
    }
  }
  float2 ts = breduce256x2(sb, sa, red);
  if (t == 0) {
    atomicAdd(&sbelow[bs], ts.x);
    atomicAdd(&sabove[bs], ts.y);
  }
}

// ---------- K5f: exact select among candidates (low 16 bits) + scale ----------
__global__ __launch_bounds__(256) void gfinal_kernel(const float* __restrict__ cand,
                                                     const unsigned int* __restrict__ ccount,
                                                     const int* __restrict__ selB,
                                                     const float* __restrict__ sbelow,
                                                     const float* __restrict__ sabove,
                                                     float* __restrict__ gstats,
                                                     float* __restrict__ nvals) {
  const int bs = blockIdx.x;
  const int t = threadIdx.x;
  const int prefix = selB[bs * 4 + 0];
  const int r2 = selB[bs * 4 + 1];
  const int n = selB[bs * 4 + 2];
  const int nbelow = selB[bs * 4 + 3];
  __shared__ unsigned int hist[256];
  __shared__ float red[256];
  __shared__ int sh_bin1, sh_r3;
  const float* cd = cand + (size_t)bs * CAP;
  int c = (int)min(ccount[bs * CPAD], (unsigned int)CAP);
  if (prefix < 0) {
    if (t == 0) {
      gstats[bs * 2 + 0] = 0.f;
      gstats[bs * 2 + 1] = 0.f;
      if ((bs & 1) == 0) nvals[bs >> 1] = 0.f;
    }
    return;
  }

  // pass 1: bits [15:8]
  hist[t] = 0;
  __syncthreads();
  for (int i = t; i < c; i += 256)
    atomicAdd(&hist[(fkey(cd[i]) >> 8) & 255u], 1u);
  __syncthreads();
  if (t == 0) {
    unsigned int rr = (unsigned int)r2, cum = 0;
    int bin = 0;
    for (; bin < 256; ++bin) {
      unsigned int h = hist[bin];
      if (cum + h > rr) break;
      cum += h;
    }
    sh_bin1 = bin;
    sh_r3 = (int)(rr - cum);
  }
  __syncthreads();
  const int bin1 = sh_bin1;
  const int r3 = sh_r3;

  // pass 2: bits [7:0]
  hist[t] = 0;
  __syncthreads();
  for (int i = t; i < c; i += 256) {
    unsigned int key = fkey(cd[i]);
    if (((key >> 8) & 255u) == (unsigned int)bin1)
      atomicAdd(&hist[key & 255u], 1u);
  }
  __syncthreads();
  __shared__ float sh_med;
  if (t == 0) {
    unsigned int rr = (unsigned int)r3, cum = 0;
    int bin = 0;
    for (; bin < 256; ++bin) {
      unsigned int h = hist[bin];
      if (cum + h > rr) break;
      cum += h;
    }
    unsigned int key = ((unsigned int)prefix << 16) |
                       ((unsigned int)bin1 << 8) | (unsigned int)bin;
    sh_med = fkey_inv(key);
  }
  __syncthreads();
  const float med = sh_med;

  float ps = 0.f;
  for (int i = t; i < c; i += 256) ps += fabsf(cd[i] - med);
  float scand = breduce256(ps, red);
  if (t == 0) {
    float nb = (float)nbelow;
    float na = (float)(n - nbelow - c);
    float num = (nb * med - sbelow[bs]) + (sabove[bs] - na * med) + scand;
    gstats[bs * 2 + 0] = med;
    gstats[bs * 2 + 1] = num / fmaxf((float)n, 1.f);
    if ((bs & 1) == 0) nvals[bs >> 1] = (float)n;
  }
}

// ---------- K6a: global error partial sums (vectorized, both signals) ----------
__global__ __launch_bounds__(256) void gerr_kernel(const float* __restrict__ inp,
                                                   const float* __restrict__ tgt,
                                                   const unsigned char* __restrict__ mask,
                                                   const float* __restrict__ gstats,
                                                   float* __restrict__ gacc) {
  const int b = blockIdx.x / PSLICE;
  const int sl = blockIdx.x % PSLICE;
  __shared__ float red[256];
  const int t = threadIdx.x;
  const float med_i = gstats[(b * 2 + 0) * 2 + 0];
  const float sc_i = fmaxf(gstats[(b * 2 + 0) * 2 + 1], EPSV);
  const float med_t = gstats[(b * 2 + 1) * 2 + 0];
  const float sc_t = fmaxf(gstats[(b * 2 + 1) * 2 + 1], EPSV);
  const float ri = 1.f / sc_i, rt = 1.f / sc_t;
  const float4* xi4 = (const float4*)(inp + (size_t)b * HWN);
  const float4* xt4 = (const float4*)(tgt + (size_t)b * HWN);
  const unsigned int* m4 = (const unsigned int*)(mask + (size_t)b * HWN);
  const int per4 = (HWN / PSLICE) / 4;
  const int s0 = sl * per4;
  float part = 0.f;
  for (int i = s0 + t; i < s0 + per4; i += 256) {
    unsigned int mm = m4[i];
    if (!mm) continue;
    float4 a = xi4[i], c = xt4[i];
    if (mm & 0x000000FFu) part += fmaxf(fabsf((a.x - med_i) * ri - (c.x - med_t) * rt), EPSV);
    if (mm & 0x0000FF00u) part += fmaxf(fabsf((a.y - med_i) * ri - (c.y - med_t) * rt), EPSV);
    if (mm & 0x00FF0000u) part += fmaxf(fabsf((a.z - med_i) * ri - (c.z - med_t) * rt), EPSV);
    if (mm & 0xFF000000u) part += fmaxf(fabsf((a.w - med_i) * ri - (c.w - med_t) * rt), EPSV);
  }
  float tp = breduce256(part, red);
  if (t == 0) atomicAdd(&gacc[b], tp);
}

// ---------- K6b: combine ----------
__global__ __launch_bounds__(64) void final_kernel(const float* __restrict__ gacc,
                                                   const float* __restrict__ nvals,
                                                   const float* __restrict__ e_patch,
                                                   float* __restrict__ out) {
  const int b = threadIdx.x;
  if (b < BB) {
    float n = nvals[b];
    float eg = sqrtf(fmaxf(gacc[b] / fmaxf(n, 1.f), EPSV));
    out[b] = 0.5f * (e_patch[b] + eg);
  }
}

extern "C" void kernel_launch(void* const* d_in, const int* in_sizes, int n_in,
                              void* d_out, int out_size, void* d_ws, size_t ws_size,
                              hipStream_t stream) {
  const float* inp = (const float*)d_in[0];
  const float* tgt = (const float*)d_in[1];
  const unsigned char* mask = (const unsigned char*)d_in[2];   // jax bool -> 1 byte
  const float* image = (const float*)d_in[3];
  const unsigned char* vmask = (const unsigned char*)d_in[4];  // jax bool -> 1 byte
  float* out = (float*)d_out;

  float* ws = (float*)d_ws;
  float* re = ws;                                   // 48960
  int* coords = (int*)(ws + 48960);                 // 9792
  float* ep = ws + 48960 + 9792;                    // 4896
  float* val = ep + 4896;                           // 4896
  float* e_patch = val + 4896;                      // 32
  float* gstats = e_patch + 32;                     // 128
  float* nvals = gstats + 128;                      // 32
  int* selA = (int*)(nvals + 32);                   // 256
  int* selB = selA + 256;                           // 256
  float* cand = (float*)(selB + 256);               // 64*CAP = 1,048,576
  // zeroed region (one contiguous memset)
  unsigned int* ghistA = (unsigned int*)(cand + (size_t)64 * CAP);  // 64*256
  unsigned int* ghistB = ghistA + 64 * 256;                         // 64*256
  unsigned int* ccount = ghistB + 64 * 256;                         // 64*CPAD
  float* sbelow = (float*)(ccount + 64 * CPAD);                     // 64
  float* sabove = sbelow + 64;                                      // 64
  float* gacc = sabove + 64;                                        // 32
  size_t zero_bytes = ((size_t)64 * 256 * 2 + 64 * CPAD + 64 + 64 + 32) * 4;
  hipMemsetAsync(ghistA, 0, zero_bytes, stream);

  // rpart (BB*TSLICE*OHW = 489,600 ints) aliases cand: topk finishes before
  // gcollect writes cand (stream-ordered), and coords is consumed by patch.
  int* rpart = (int*)cand;

  edge_resize_kernel<<<(BB * OHW * 4) / 256, 256, 0, stream>>>(image, vmask, re);
  topk_rank_kernel<<<BB * TSLICE, 256, 0, stream>>>(re, rpart);
  topk_write_kernel<<<BB, 256, 0, stream>>>(rpart, coords);
  patch_kernel<<<BB * KTOP, 64, 0, stream>>>(inp, tgt, mask, coords, ep, val);
  preduce_kernel<<<BB, 256, 0, stream>>>(ep, val, e_patch);
  gpassA_kernel<<<BB * PSLICE, 256, 0, stream>>>(inp, tgt, mask, ghistA);
  gselA_kernel<<<BB * 2, 64, 0, stream>>>(ghistA, selA);
  gpassB_kernel<<<BB * PSLICE, 256, 0, stream>>>(inp, tgt, mask, selA, ghistB);
  gselB_kernel<<<BB * 2, 64, 0, stream>>>(ghistB, selA, selB);
  gcollect_kernel<<<BB * 2 * NSLICE, 256, 0, stream>>>(inp, tgt, mask, selB, cand, ccount, sbelow, sabove);
  gfinal_kernel<<<BB * 2, 256, 0, stream>>>(cand, ccount, selB, sbelow, sabove, gstats, nvals);
  gerr_kernel<<<BB * PSLICE, 256, 0, stream>>>(inp, tgt, mask, gstats, gacc);
  final_kernel<<<1, 64, 0, stream>>>(gacc, nvals, e_patch, out);
}